// Round 1
// baseline (539.499 us; speedup 1.0000x reference)
//
#include <hip/hip_runtime.h>

// Problem constants
#define B_   16
#define T_   256
#define V_   10000
#define C_   4096
#define H_   256
#define NC_  128
#define CAP_ 224   // max words per cluster we handle (mean 78, sd 8.8 -> 16 sigma)

typedef __bf16 bf16x8 __attribute__((ext_vector_type(8)));
typedef float  f32x4  __attribute__((ext_vector_type(4)));

__device__ inline unsigned short f2bf(float f){
  unsigned int u = __float_as_uint(f);
  u += 0x7FFFu + ((u >> 16) & 1u);
  return (unsigned short)(u >> 16);
}

__device__ inline f32x4 mfma16(bf16x8 a, bf16x8 b, f32x4 c){
  return __builtin_amdgcn_mfma_f32_16x16x32_bf16(a, b, c, 0, 0, 0);
}

// ---------------------------------------------------------------------------
// Transpose-pack projection (z=0) and terminal_w[0..3] (z=1..4) into bf16 N x K
__global__ void k_tpack(const float* __restrict__ proj, const float* __restrict__ tw,
                        unsigned short* __restrict__ projT, unsigned short* __restrict__ WT){
  int z = blockIdx.y;
  int dcol = blockIdx.x;          // output row (source column)
  int h = threadIdx.x;
  const float* src = (z == 0) ? proj : (tw + (size_t)(z-1)*65536);
  unsigned short* dst = (z == 0) ? projT : (WT + (size_t)(z-1)*65536);
  dst[dcol*256 + h] = f2bf(src[h*256 + dcol]);
}

// ---------------------------------------------------------------------------
// Row pack fp32 -> bf16, optional 0.5*||row||^2
__global__ __launch_bounds__(256) void k_pack(const float* __restrict__ X,
                                              unsigned short* __restrict__ Xbf,
                                              float* __restrict__ nrm){
  __shared__ float red[4];
  int r = blockIdx.x, d = threadIdx.x;
  float x = X[r*256 + d];
  Xbf[r*256 + d] = f2bf(x);
  if (nrm){
    float v = x*x;
    #pragma unroll
    for (int m = 1; m < 64; m <<= 1) v += __shfl_xor(v, m);
    if ((d & 63) == 0) red[d >> 6] = v;
    __syncthreads();
    if (d == 0) nrm[r] = 0.5f*(red[0]+red[1]+red[2]+red[3]);
  }
}

// ---------------------------------------------------------------------------
// Generic 32x32-tile MFMA GEMM: C = epilogue(A[MxK=256] @ Bt[N=256xK=256]^T)
__global__ __launch_bounds__(64) void k_gemm(
    const unsigned short* __restrict__ A, const unsigned short* __restrict__ Bt,
    const float* __restrict__ bias, const float* __restrict__ res,
    float* __restrict__ Cf, unsigned short* __restrict__ Cbf, int M, int relu)
{
  int r0 = blockIdx.x*32, c0 = blockIdx.y*32;
  int ln = threadIdx.x, m16 = ln & 15, q = ln >> 4;
  int ra0 = r0 + m16;      if (ra0 > M-1) ra0 = M-1;
  int ra1 = r0 + 16 + m16; if (ra1 > M-1) ra1 = M-1;
  const unsigned short* a0p = A + (size_t)ra0*256;
  const unsigned short* a1p = A + (size_t)ra1*256;
  const unsigned short* b0p = Bt + (size_t)(c0 + m16)*256;
  const unsigned short* b1p = b0p + 16*256;
  f32x4 acc[2][2];
  #pragma unroll
  for (int i = 0; i < 2; ++i)
    #pragma unroll
    for (int jx = 0; jx < 2; ++jx) acc[i][jx] = (f32x4){0.f,0.f,0.f,0.f};
  #pragma unroll
  for (int kt = 0; kt < 8; ++kt){
    int ko = kt*32 + q*8;
    bf16x8 a0 = *(const bf16x8*)(a0p + ko);
    bf16x8 a1 = *(const bf16x8*)(a1p + ko);
    bf16x8 b0 = *(const bf16x8*)(b0p + ko);
    bf16x8 b1 = *(const bf16x8*)(b1p + ko);
    acc[0][0] = mfma16(a0, b0, acc[0][0]);
    acc[0][1] = mfma16(a0, b1, acc[0][1]);
    acc[1][0] = mfma16(a1, b0, acc[1][0]);
    acc[1][1] = mfma16(a1, b1, acc[1][1]);
  }
  #pragma unroll
  for (int mi = 0; mi < 2; ++mi){
    #pragma unroll
    for (int ni = 0; ni < 2; ++ni){
      #pragma unroll
      for (int r = 0; r < 4; ++r){
        int row = r0 + mi*16 + q*4 + r;
        int col = c0 + ni*16 + m16;
        if (row < M){
          float v = acc[mi][ni][r];
          if (bias) v += bias[col];
          if (relu) v = fmaxf(v, 0.f);
          if (res)  v += res[(size_t)row*256 + col];
          if (Cf)  Cf [(size_t)row*256 + col] = v;
          if (Cbf) Cbf[(size_t)row*256 + col] = f2bf(v);
        }
      }
    }
  }
}

// ---------------------------------------------------------------------------
// phi finish: phi = XP - nrm; rowmax m; E = exp(phi - m)
__global__ __launch_bounds__(256) void k_finish(const float* __restrict__ XP,
                                                const float* __restrict__ nrm,
                                                float* __restrict__ E, float* __restrict__ mrow){
  __shared__ float red[4];
  int r = blockIdx.x, d = threadIdx.x;
  float phi = XP[(size_t)r*256 + d] - nrm[r];
  float m = phi;
  #pragma unroll
  for (int k = 1; k < 64; k <<= 1) m = fmaxf(m, __shfl_xor(m, k));
  if ((d & 63) == 0) red[d >> 6] = m;
  __syncthreads();
  m = fmaxf(fmaxf(red[0], red[1]), fmaxf(red[2], red[3]));
  E[(size_t)r*256 + d] = __expf(phi - m);
  if (d == 0) mrow[r] = m;
}

// ---------------------------------------------------------------------------
// S[d] = sum_c exp(lpy[c,d]) = sum_c Eb[c,d]*exp(mb[c])
__global__ void k_S(const float* __restrict__ Eb, const float* __restrict__ mb,
                    float* __restrict__ S){
  int g = blockIdx.x, d = threadIdx.x;
  float s = 0.f;
  for (int c = g*64; c < g*64 + 64; ++c)
    s += Eb[(size_t)c*256 + d]*__expf(mb[c]);
  atomicAdd(&S[d], s);
}

// ga[c] = 1/(Ea[c].S)  (= exp(ma - lse_row)),  gb[c] = exp(mb[c])
__global__ void k_ga(const float* __restrict__ Ea, const float* __restrict__ S,
                     const float* __restrict__ mb, float* __restrict__ ga, float* __restrict__ gb){
  int c = blockIdx.x*8 + (threadIdx.x >> 5);
  int l = threadIdx.x & 31;
  float dot = 0.f;
  #pragma unroll
  for (int kk = 0; kk < 8; ++kk){ int d = l + kk*32; dot = fmaf(Ea[(size_t)c*256 + d], S[d], dot); }
  #pragma unroll
  for (int m = 1; m < 32; m <<= 1) dot += __shfl_xor(dot, m);
  if (l == 0){ ga[c] = 1.0f/dot; gb[c] = __expf(mb[c]); }
}

// Eap = bf16(Ea*ga), Ebp = bf16(Eb*gb)
__global__ void k_packP(const float* __restrict__ Ea, const float* __restrict__ Eb,
                        const float* __restrict__ ga, const float* __restrict__ gb,
                        unsigned short* __restrict__ Eap, unsigned short* __restrict__ Ebp){
  int r = blockIdx.x, d = threadIdx.x;
  Eap[(size_t)r*256 + d] = f2bf(Ea[(size_t)r*256 + d]*ga[r]);
  Ebp[(size_t)r*256 + d] = f2bf(Eb[(size_t)r*256 + d]*gb[r]);
}

// ---------------------------------------------------------------------------
// start vector: fx through 5 layers, then phi(fx) -> Eafx, mafx
__global__ __launch_bounds__(256) void k_fx(
  const float* __restrict__ se, const float* __restrict__ sw, const float* __restrict__ sb,
  const float* __restrict__ proj, float* __restrict__ Eafx, float* __restrict__ mafx)
{
  __shared__ float xv[256], hv[256], red[4];
  int t = threadIdx.x;
  hv[t] = se[t];
  __syncthreads();
  float acc = sb[t];
  for (int h = 0; h < 256; ++h) acc = fmaf(hv[h], sw[h*256 + t], acc);
  __syncthreads();
  xv[t] = acc;
  __syncthreads();
  // res block 1
  acc = sb[256 + t];
  for (int h = 0; h < 256; ++h) acc = fmaf(xv[h], sw[65536 + h*256 + t], acc);
  hv[t] = fmaxf(acc, 0.f);
  __syncthreads();
  acc = sb[512 + t];
  for (int h = 0; h < 256; ++h) acc = fmaf(hv[h], sw[2*65536 + h*256 + t], acc);
  float xnew = xv[t] + fmaxf(acc, 0.f);
  __syncthreads();
  xv[t] = xnew;
  __syncthreads();
  // res block 2
  acc = sb[768 + t];
  for (int h = 0; h < 256; ++h) acc = fmaf(xv[h], sw[3*65536 + h*256 + t], acc);
  hv[t] = fmaxf(acc, 0.f);
  __syncthreads();
  acc = sb[1024 + t];
  for (int h = 0; h < 256; ++h) acc = fmaf(hv[h], sw[4*65536 + h*256 + t], acc);
  xnew = xv[t] + fmaxf(acc, 0.f);
  __syncthreads();
  xv[t] = xnew;
  __syncthreads();
  // phi(fx)
  float v = xv[t]*xv[t];
  #pragma unroll
  for (int m = 1; m < 64; m <<= 1) v += __shfl_xor(v, m);
  if ((t & 63) == 0) red[t >> 6] = v;
  __syncthreads();
  float nx = red[0]+red[1]+red[2]+red[3];
  float px = -0.5f*nx;
  for (int h = 0; h < 256; ++h) px = fmaf(xv[h], proj[h*256 + t], px);
  __syncthreads();
  float m2 = px;
  #pragma unroll
  for (int m = 1; m < 64; m <<= 1) m2 = fmaxf(m2, __shfl_xor(m2, m));
  if ((t & 63) == 0) red[t >> 6] = m2;
  __syncthreads();
  m2 = fmaxf(fmaxf(red[0], red[1]), fmaxf(red[2], red[3]));
  Eafx[t] = __expf(px - m2);
  if (t == 0) mafx[0] = m2;
}

// ---------------------------------------------------------------------------
// start_lp[c] = z[c] - lse(z),  z[c] = log(Eafx . Eb[c]) + mafx + mb[c]
__global__ __launch_bounds__(1024) void k_start(
  const float* __restrict__ Eafx, const float* __restrict__ mafx,
  const float* __restrict__ Eb, const float* __restrict__ mb, float* __restrict__ start_lp)
{
  __shared__ float z[4096];
  __shared__ float ef[256];
  __shared__ float red[16];
  int tid = threadIdx.x;
  if (tid < 256) ef[tid] = Eafx[tid];
  __syncthreads();
  int rl = tid >> 4, l = tid & 15;
  float mfx = mafx[0];
  for (int p = 0; p < 64; ++p){
    int c = p*64 + rl;
    float dot = 0.f;
    #pragma unroll
    for (int k = 0; k < 16; ++k){ int d = l + k*16; dot = fmaf(ef[d], Eb[(size_t)c*256 + d], dot); }
    #pragma unroll
    for (int m = 1; m < 16; m <<= 1) dot += __shfl_xor(dot, m);
    if (l == 0) z[c] = __logf(dot) + mfx + mb[c];
  }
  __syncthreads();
  float lm = -1e30f;
  for (int c = tid; c < 4096; c += 1024) lm = fmaxf(lm, z[c]);
  #pragma unroll
  for (int m = 1; m < 64; m <<= 1) lm = fmaxf(lm, __shfl_xor(lm, m));
  if ((tid & 63) == 0) red[tid >> 6] = lm;
  __syncthreads();
  float gm = red[0];
  for (int i = 1; i < 16; ++i) gm = fmaxf(gm, red[i]);
  __syncthreads();
  float ls = 0.f;
  for (int c = tid; c < 4096; c += 1024) ls += __expf(z[c] - gm);
  #pragma unroll
  for (int m = 1; m < 64; m <<= 1) ls += __shfl_xor(ls, m);
  if ((tid & 63) == 0) red[tid >> 6] = ls;
  __syncthreads();
  float gs = 0.f;
  for (int i = 0; i < 16; ++i) gs += red[i];
  float lse = gm + __logf(gs);
  for (int c = tid; c < 4096; c += 1024) start_lp[c] = z[c] - lse;
}

// ---------------------------------------------------------------------------
// build per-cluster word lists
__global__ void k_lists(const int* __restrict__ w2s, int* __restrict__ cnt, int* __restrict__ list){
  int v = blockIdx.x*256 + threadIdx.x;
  if (v < V_){
    int k = w2s[v*32] >> 5;
    int pos = atomicAdd(&cnt[k], 1);
    if (pos < CAP_) list[k*CAP_ + pos] = v;
  }
}

// ---------------------------------------------------------------------------
// per-cluster emit log-softmax: emit_col[v*32 + i] = emit_lp[k*32+i, v]
__global__ __launch_bounds__(256) void k_emit(
    const float* __restrict__ Ep, const float* __restrict__ mp,
    const float* __restrict__ Et, const float* __restrict__ mt,
    const int* __restrict__ cnt, const int* __restrict__ list,
    float* __restrict__ emit_col)
{
  __shared__ float Eps[32*260];
  __shared__ float lbuf[32*CAP_];
  __shared__ int   vls[CAP_];
  __shared__ float mps[32];
  int k = blockIdx.x, tid = threadIdx.x;
  for (int idx = tid; idx < 32*256; idx += 256){
    int i = idx >> 8, d = idx & 255;
    Eps[i*260 + d] = Ep[(size_t)(k*32 + i)*256 + d];
  }
  if (tid < 32) mps[tid] = mp[k*32 + tid];
  int n = cnt[k]; if (n > CAP_) n = CAP_;
  for (int w = tid; w < n; w += 256) vls[w] = list[k*CAP_ + w];
  __syncthreads();
  int i = tid >> 3, l = tid & 7;
  const float* Eprow = &Eps[i*260];
  float mpi = mps[i];
  float mrun = -1e30f, srun = 0.f;
  for (int w = 0; w < n; ++w){
    int v = vls[w];
    const float* etr = Et + (size_t)v*256;
    float dot = 0.f;
    #pragma unroll
    for (int g = 0; g < 32; ++g){
      int d = g*8 + l;
      dot = fmaf(Eprow[d], etr[d], dot);
    }
    dot += __shfl_xor(dot, 1);
    dot += __shfl_xor(dot, 2);
    dot += __shfl_xor(dot, 4);
    float logit = __logf(dot) + mpi + mt[v];
    float nm = fmaxf(mrun, logit);
    srun = srun*__expf(mrun - nm) + __expf(logit - nm);
    mrun = nm;
    if (l == 0) lbuf[i*CAP_ + w] = logit;
  }
  float den = mrun + __logf(srun);
  __syncthreads();
  for (int w = l; w < n; w += 8){
    emit_col[(size_t)vls[w]*32 + i] = lbuf[i*CAP_ + w] - den;
  }
}

// ---------------------------------------------------------------------------
// P blocks: P[bt][i][j] = exp(trans_lp[kp*32+i, kc*32+j]) via bf16 MFMA
__global__ __launch_bounds__(64) void k_pblocks(
  const unsigned short* __restrict__ Eap, const unsigned short* __restrict__ Ebp,
  const int* __restrict__ text, const int* __restrict__ w2s, float* __restrict__ P)
{
  int bt = blockIdx.x;
  int b = bt / 255, th = bt % 255;
  int vp = text[b*256 + th], vc = text[b*256 + th + 1];
  int bp = w2s[vp*32], bc = w2s[vc*32];
  int ln = threadIdx.x, m16 = ln & 15, q = ln >> 4;
  const unsigned short* a0p = Eap + (size_t)(bp + m16)*256;
  const unsigned short* a1p = a0p + 16*256;
  const unsigned short* b0p = Ebp + (size_t)(bc + m16)*256;
  const unsigned short* b1p = b0p + 16*256;
  f32x4 acc[2][2];
  #pragma unroll
  for (int i = 0; i < 2; ++i)
    #pragma unroll
    for (int jx = 0; jx < 2; ++jx) acc[i][jx] = (f32x4){0.f,0.f,0.f,0.f};
  #pragma unroll
  for (int kt = 0; kt < 8; ++kt){
    int ko = kt*32 + q*8;
    bf16x8 a0 = *(const bf16x8*)(a0p + ko);
    bf16x8 a1 = *(const bf16x8*)(a1p + ko);
    bf16x8 b0 = *(const bf16x8*)(b0p + ko);
    bf16x8 b1 = *(const bf16x8*)(b1p + ko);
    acc[0][0] = mfma16(a0, b0, acc[0][0]);
    acc[0][1] = mfma16(a0, b1, acc[0][1]);
    acc[1][0] = mfma16(a1, b0, acc[1][0]);
    acc[1][1] = mfma16(a1, b1, acc[1][1]);
  }
  float* Pout = P + (size_t)bt*1024;
  #pragma unroll
  for (int mi = 0; mi < 2; ++mi){
    #pragma unroll
    for (int ni = 0; ni < 2; ++ni){
      #pragma unroll
      for (int r = 0; r < 4; ++r){
        int row = mi*16 + q*4 + r;
        int col = ni*16 + m16;
        Pout[row*32 + col] = acc[mi][ni][r];
      }
    }
  }
}

// ---------------------------------------------------------------------------
// Eem[b][t][j] = exp(emit_col[text[b,t]*32 + j])
__global__ void k_eem(const int* __restrict__ text, const float* __restrict__ emit_col,
                      float* __restrict__ Eem){
  int idx = blockIdx.x*256 + threadIdx.x;   // < 131072
  int j = idx & 31, t = (idx >> 5) & 255, b = idx >> 13;
  int v = text[b*256 + t];
  Eem[idx] = __expf(emit_col[(size_t)v*32 + j]);
}

// ---------------------------------------------------------------------------
// forward scan in exp space, one wave per batch
__global__ __launch_bounds__(64) void k_scan(
  const float* __restrict__ P, const float* __restrict__ Eem,
  const float* __restrict__ start_lp, const float* __restrict__ emit_col,
  const int* __restrict__ text, const int* __restrict__ w2s, float* __restrict__ out)
{
  int b = blockIdx.x;
  int ln = threadIdx.x;
  int j = ln & 31, h = ln >> 5;
  int v0 = text[b*256];
  int k0 = w2s[v0*32];
  float a0 = start_lp[k0 + j] + emit_col[(size_t)v0*32 + j];
  float m = a0;
  #pragma unroll
  for (int k = 1; k < 32; k <<= 1) m = fmaxf(m, __shfl_xor(m, k));
  float ae = __expf(a0 - m);
  float tot = ae;
  #pragma unroll
  for (int k = 1; k < 32; k <<= 1) tot += __shfl_xor(tot, k);
  float aval = ae / tot;
  float logtot = m + __logf(tot);
  const float* Pb = P + (size_t)b*255*1024;
  float pv[16], pn[16];
  #pragma unroll
  for (int s = 0; s < 16; ++s) pv[s] = Pb[(h*16 + s)*32 + j];
  float ev = Eem[(b*256 + 1)*32 + j];
  for (int t = 1; t < 256; ++t){
    float en = 0.f;
    if (t < 255){
      const float* Pn = Pb + (size_t)t*1024;
      #pragma unroll
      for (int s = 0; s < 16; ++s) pn[s] = Pn[(h*16 + s)*32 + j];
      en = Eem[(b*256 + t + 1)*32 + j];
    }
    float partial = 0.f;
    #pragma unroll
    for (int s = 0; s < 16; ++s)
      partial = fmaf(__shfl(aval, h*16 + s), pv[s], partial);
    float dotj = partial + __shfl_xor(partial, 32);
    float anew = dotj * ev;
    float ts = anew;
    #pragma unroll
    for (int k = 1; k < 32; k <<= 1) ts += __shfl_xor(ts, k);
    float inv = 1.0f / ts;
    aval = anew * inv;
    logtot += __logf(ts);
    #pragma unroll
    for (int s = 0; s < 16; ++s) pv[s] = pn[s];
    ev = en;
  }
  if (ln == 0) out[b] = logtot;
}

// ---------------------------------------------------------------------------
extern "C" void kernel_launch(void* const* d_in, const int* in_sizes, int n_in,
                              void* d_out, int out_size, void* d_ws, size_t ws_size,
                              hipStream_t stream)
{
  (void)in_sizes; (void)n_in; (void)out_size; (void)ws_size;
  const int*   text      = (const int*)  d_in[0];
  const float* start_emb = (const float*)d_in[1];
  const float* start_w   = (const float*)d_in[2];
  const float* start_b   = (const float*)d_in[3];
  const float* state_emb = (const float*)d_in[4];
  const float* next_emb  = (const float*)d_in[5];
  const float* pre_emb   = (const float*)d_in[6];
  const float* term_w    = (const float*)d_in[7];
  const float* term_b    = (const float*)d_in[8];
  const float* term_emb  = (const float*)d_in[9];
  const float* proj      = (const float*)d_in[10];
  const int*   w2s       = (const int*)  d_in[11];
  float* out = (float*)d_out;

  char* base = (char*)d_ws;
  size_t off = 0;
  auto alloc = [&](size_t bytes)->char*{
    char* p = base + off;
    off += (bytes + 255) & ~(size_t)255;
    return p;
  };
  unsigned short* projT = (unsigned short*)alloc((size_t)65536*2);
  unsigned short* WT    = (unsigned short*)alloc((size_t)4*65536*2);
  float* Eafx = (float*)alloc(256*4);
  float* mafx = (float*)alloc(256);
  unsigned short* Abf  = (unsigned short*)alloc((size_t)V_*256*2);
  unsigned short* Hbf1 = (unsigned short*)alloc((size_t)C_*256*2);
  unsigned short* Hbf2 = (unsigned short*)alloc((size_t)C_*256*2);
  float* X2  = (float*)alloc((size_t)C_*256*4);
  float* FP  = (float*)alloc((size_t)C_*256*4);
  float* XP  = (float*)alloc((size_t)V_*256*4);
  float* nrm = (float*)alloc((size_t)V_*4);
  float* Ea  = (float*)alloc((size_t)C_*256*4);
  float* ma  = (float*)alloc((size_t)C_*4);
  float* Eb  = (float*)alloc((size_t)C_*256*4);
  float* mb  = (float*)alloc((size_t)C_*4);
  float* Ep  = (float*)alloc((size_t)C_*256*4);
  float* mpp = (float*)alloc((size_t)C_*4);
  float* Et  = (float*)alloc((size_t)V_*256*4);
  float* mt  = (float*)alloc((size_t)V_*4);
  float* S   = (float*)alloc(256*4);
  float* ga  = (float*)alloc((size_t)C_*4);
  float* gb  = (float*)alloc((size_t)C_*4);
  unsigned short* Eap = (unsigned short*)alloc((size_t)C_*256*2);
  unsigned short* Ebp = (unsigned short*)alloc((size_t)C_*256*2);
  float* start_lp = (float*)alloc((size_t)C_*4);
  int* cnt  = (int*)alloc(128*4);
  int* list = (int*)alloc((size_t)128*CAP_*4);
  float* emit_col = (float*)alloc((size_t)V_*32*4);
  float* P   = (float*)alloc((size_t)4080*1024*4);
  float* Eem = (float*)alloc((size_t)B_*T_*32*4);

  hipMemsetAsync(S, 0, 256*4, stream);
  hipMemsetAsync(cnt, 0, 128*4, stream);

  k_tpack<<<dim3(256,5), 256, 0, stream>>>(proj, term_w, projT, WT);
  k_fx<<<1, 256, 0, stream>>>(start_emb, start_w, start_b, proj, Eafx, mafx);

  // preterminal MLP (4 layers, bf16 MFMA, fp32 residuals)
  k_pack<<<C_, 256, 0, stream>>>(pre_emb, Abf, nullptr);
  k_gemm<<<dim3(128,8), 64, 0, stream>>>(Abf,  WT + 0*65536, term_b + 0,   nullptr, nullptr, Hbf1, C_, 1);
  k_gemm<<<dim3(128,8), 64, 0, stream>>>(Hbf1, WT + 1*65536, term_b + 256, pre_emb, X2,      Hbf2, C_, 1);
  k_gemm<<<dim3(128,8), 64, 0, stream>>>(Hbf2, WT + 2*65536, term_b + 512, nullptr, nullptr, Hbf1, C_, 1);
  k_gemm<<<dim3(128,8), 64, 0, stream>>>(Hbf1, WT + 3*65536, term_b + 768, X2,      FP,      nullptr, C_, 1);

  // phi(state_emb) -> Ea, ma
  k_pack<<<C_, 256, 0, stream>>>(state_emb, Abf, nrm);
  k_gemm<<<dim3(128,8), 64, 0, stream>>>(Abf, projT, nullptr, nullptr, XP, nullptr, C_, 0);
  k_finish<<<C_, 256, 0, stream>>>(XP, nrm, Ea, ma);
  // phi(next_state_emb) -> Eb, mb; S
  k_pack<<<C_, 256, 0, stream>>>(next_emb, Abf, nrm);
  k_gemm<<<dim3(128,8), 64, 0, stream>>>(Abf, projT, nullptr, nullptr, XP, nullptr, C_, 0);
  k_finish<<<C_, 256, 0, stream>>>(XP, nrm, Eb, mb);
  k_S<<<64, 256, 0, stream>>>(Eb, mb, S);
  // phi(terminal_emb) -> Et, mt
  k_pack<<<V_, 256, 0, stream>>>(term_emb, Abf, nrm);
  k_gemm<<<dim3(313,8), 64, 0, stream>>>(Abf, projT, nullptr, nullptr, XP, nullptr, V_, 0);
  k_finish<<<V_, 256, 0, stream>>>(XP, nrm, Et, mt);
  // phi(fp) -> Ep, mpp
  k_pack<<<C_, 256, 0, stream>>>(FP, Abf, nrm);
  k_gemm<<<dim3(128,8), 64, 0, stream>>>(Abf, projT, nullptr, nullptr, XP, nullptr, C_, 0);
  k_finish<<<C_, 256, 0, stream>>>(XP, nrm, Ep, mpp);

  k_ga<<<512, 256, 0, stream>>>(Ea, S, mb, ga, gb);
  k_packP<<<C_, 256, 0, stream>>>(Ea, Eb, ga, gb, Eap, Ebp);
  k_start<<<1, 1024, 0, stream>>>(Eafx, mafx, Eb, mb, start_lp);
  k_lists<<<40, 256, 0, stream>>>(w2s, cnt, list);
  k_emit<<<128, 256, 0, stream>>>(Ep, mpp, Et, mt, cnt, list, emit_col);
  k_pblocks<<<4080, 64, 0, stream>>>(Eap, Ebp, text, w2s, P);
  k_eem<<<512, 256, 0, stream>>>(text, emit_col, Eem);
  k_scan<<<16, 64, 0, stream>>>(P, Eem, start_lp, emit_col, text, w2s, out);
}

// Round 2
// 360.759 us; speedup vs baseline: 1.4955x; 1.4955x over previous
//
#include <hip/hip_runtime.h>

#define B_   16
#define T_   256
#define V_   10000
#define C_   4096
#define H_   256
#define NC_  128
#define CAP_ 224
#define MST  33   // LDS matrix stride (32 + 1 pad)

typedef __bf16 bf16x8 __attribute__((ext_vector_type(8)));
typedef unsigned short u16x8 __attribute__((ext_vector_type(8)));
typedef float  f32x4  __attribute__((ext_vector_type(4)));

__device__ inline unsigned short f2bf(float f){
  unsigned int u = __float_as_uint(f);
  u += 0x7FFFu + ((u >> 16) & 1u);
  return (unsigned short)(u >> 16);
}
__device__ inline float bf2f(unsigned short u){
  return __uint_as_float(((unsigned int)u) << 16);
}
__device__ inline f32x4 mfma16(bf16x8 a, bf16x8 b, f32x4 c){
  return __builtin_amdgcn_mfma_f32_16x16x32_bf16(a, b, c, 0, 0, 0);
}
__device__ inline bf16x8 load_cvt8(const float* p){
  u16x8 u;
  #pragma unroll
  for (int i = 0; i < 8; ++i) u[i] = f2bf(p[i]);
  return __builtin_bit_cast(bf16x8, u);
}

// ---------------------------------------------------------------------------
// Transpose-pack projection (z=0) and terminal_w[0..3] (z=1..4) into bf16 NxK
__global__ void k_tpack(const float* __restrict__ proj, const float* __restrict__ tw,
                        unsigned short* __restrict__ projT, unsigned short* __restrict__ WT){
  int z = blockIdx.y;
  int dcol = blockIdx.x;
  int h = threadIdx.x;
  const float* src = (z == 0) ? proj : (tw + (size_t)(z-1)*65536);
  unsigned short* dst = (z == 0) ? projT : (WT + (size_t)(z-1)*65536);
  dst[dcol*256 + h] = f2bf(src[h*256 + dcol]);
}

// ---------------------------------------------------------------------------
// Fused MLP layer: C = res + relu(A @ Bt^T + bias), A fp32 converted in-register
__global__ __launch_bounds__(256) void k_mlp(const float* __restrict__ A,
    const unsigned short* __restrict__ Bt, const float* __restrict__ bias,
    const float* __restrict__ res, float* __restrict__ C)
{
  int r0 = blockIdx.x*32;
  int tid = threadIdx.x;
  int w = tid >> 6, ln = tid & 63;
  int m16 = ln & 15, q = ln >> 4;
  int c0 = w*64;
  const float* a0 = A + (size_t)(r0 + m16)*256 + q*8;
  const float* a1 = a0 + 16*256;
  const unsigned short* bp0 = Bt + (size_t)(c0 + m16)*256 + q*8;
  f32x4 acc[2][4];
  #pragma unroll
  for (int i = 0; i < 2; ++i)
    #pragma unroll
    for (int jx = 0; jx < 4; ++jx) acc[i][jx] = (f32x4){0.f,0.f,0.f,0.f};
  #pragma unroll
  for (int kt = 0; kt < 8; ++kt){
    bf16x8 af0 = load_cvt8(a0 + kt*32);
    bf16x8 af1 = load_cvt8(a1 + kt*32);
    #pragma unroll
    for (int cj = 0; cj < 4; ++cj){
      bf16x8 bfj = *(const bf16x8*)(bp0 + (size_t)cj*16*256 + kt*32);
      acc[0][cj] = mfma16(af0, bfj, acc[0][cj]);
      acc[1][cj] = mfma16(af1, bfj, acc[1][cj]);
    }
  }
  #pragma unroll
  for (int ri = 0; ri < 2; ++ri){
    #pragma unroll
    for (int cj = 0; cj < 4; ++cj){
      #pragma unroll
      for (int r = 0; r < 4; ++r){
        int row = r0 + ri*16 + q*4 + r;
        int col = c0 + cj*16 + m16;
        float v = acc[ri][cj][r] + bias[col];
        v = fmaxf(v, 0.f);
        if (res) v += res[(size_t)row*256 + col];
        C[(size_t)row*256 + col] = v;
      }
    }
  }
}

// ---------------------------------------------------------------------------
// phi GEMM core: 32-row slab x full 256 cols, A fp32 cvt in-register.
// Also computes 0.5*||row||^2 into lnrm (wave 0).
__device__ inline void phi_core(const float* __restrict__ A,
    const unsigned short* __restrict__ Bt, int r0, int M, int w, int ln,
    f32x4 acc[2][4], float* lnrm)
{
  int m16 = ln & 15, q = ln >> 4;
  int c0 = w*64;
  int ra0 = r0 + m16;      if (ra0 > M-1) ra0 = M-1;
  int ra1 = r0 + 16 + m16; if (ra1 > M-1) ra1 = M-1;
  const float* a0 = A + (size_t)ra0*256 + q*8;
  const float* a1 = A + (size_t)ra1*256 + q*8;
  const unsigned short* bp0 = Bt + (size_t)(c0 + m16)*256 + q*8;
  float ss0 = 0.f, ss1 = 0.f;
  #pragma unroll
  for (int kt = 0; kt < 8; ++kt){
    float av0[8], av1[8];
    #pragma unroll
    for (int i2 = 0; i2 < 8; ++i2){ av0[i2] = a0[kt*32 + i2]; av1[i2] = a1[kt*32 + i2]; }
    u16x8 u0, u1;
    #pragma unroll
    for (int i2 = 0; i2 < 8; ++i2){
      u0[i2] = f2bf(av0[i2]); u1[i2] = f2bf(av1[i2]);
      ss0 = fmaf(av0[i2], av0[i2], ss0);
      ss1 = fmaf(av1[i2], av1[i2], ss1);
    }
    bf16x8 af0 = __builtin_bit_cast(bf16x8, u0);
    bf16x8 af1 = __builtin_bit_cast(bf16x8, u1);
    #pragma unroll
    for (int cj = 0; cj < 4; ++cj){
      bf16x8 bfj = *(const bf16x8*)(bp0 + (size_t)cj*16*256 + kt*32);
      acc[0][cj] = mfma16(af0, bfj, acc[0][cj]);
      acc[1][cj] = mfma16(af1, bfj, acc[1][cj]);
    }
  }
  ss0 += __shfl_xor(ss0, 16); ss0 += __shfl_xor(ss0, 32);
  ss1 += __shfl_xor(ss1, 16); ss1 += __shfl_xor(ss1, 32);
  if (w == 0 && q == 0){ lnrm[m16] = 0.5f*ss0; lnrm[16 + m16] = 0.5f*ss1; }
}

// ---------------------------------------------------------------------------
// phiB: Ebp = bf16(exp(phi))  (= Eb * e^{mb}), S[d] += column sums (atomic)
__global__ __launch_bounds__(256) void k_phiB(const float* __restrict__ A,
    const unsigned short* __restrict__ projT, unsigned short* __restrict__ Ebp,
    float* __restrict__ S)
{
  __shared__ float lnrm[32];
  int r0 = blockIdx.x*32;
  int tid = threadIdx.x;
  int w = tid >> 6, ln = tid & 63;
  int m16 = ln & 15, q = ln >> 4;
  f32x4 acc[2][4];
  #pragma unroll
  for (int i = 0; i < 2; ++i)
    #pragma unroll
    for (int jx = 0; jx < 4; ++jx) acc[i][jx] = (f32x4){0.f,0.f,0.f,0.f};
  phi_core(A, projT, r0, C_, w, ln, acc, lnrm);
  __syncthreads();
  int c0 = w*64;
  #pragma unroll
  for (int cj = 0; cj < 4; ++cj){
    int col = c0 + cj*16 + m16;
    float cs = 0.f;
    #pragma unroll
    for (int ri = 0; ri < 2; ++ri){
      #pragma unroll
      for (int r = 0; r < 4; ++r){
        int row = ri*16 + q*4 + r;
        float e = __expf(acc[ri][cj][r] - lnrm[row]);
        Ebp[(size_t)(r0 + row)*256 + col] = f2bf(e);
        cs += e;
      }
    }
    cs += __shfl_xor(cs, 16); cs += __shfl_xor(cs, 32);
    if (q == 0) atomicAdd(&S[col], cs);
  }
}

// ---------------------------------------------------------------------------
// phiA: Eap = bf16( exp(phi - m) / sum_d exp(phi-m)*S[d] )
__global__ __launch_bounds__(256) void k_phiA(const float* __restrict__ A,
    const unsigned short* __restrict__ projT, const float* __restrict__ S,
    unsigned short* __restrict__ Eap)
{
  __shared__ float lnrm[32];
  __shared__ float sS[256];
  __shared__ float wrow[4][32];
  __shared__ float wden[4][32];
  int r0 = blockIdx.x*32;
  int tid = threadIdx.x;
  int w = tid >> 6, ln = tid & 63;
  int m16 = ln & 15, q = ln >> 4;
  sS[tid] = S[tid];
  f32x4 acc[2][4];
  #pragma unroll
  for (int i = 0; i < 2; ++i)
    #pragma unroll
    for (int jx = 0; jx < 4; ++jx) acc[i][jx] = (f32x4){0.f,0.f,0.f,0.f};
  phi_core(A, projT, r0, C_, w, ln, acc, lnrm);
  __syncthreads();
  int c0 = w*64;
  float mrow[2][4];
  #pragma unroll
  for (int ri = 0; ri < 2; ++ri){
    #pragma unroll
    for (int r = 0; r < 4; ++r){
      int row = ri*16 + q*4 + r;
      float mv = -1e30f;
      #pragma unroll
      for (int cj = 0; cj < 4; ++cj){
        acc[ri][cj][r] -= lnrm[row];
        mv = fmaxf(mv, acc[ri][cj][r]);
      }
      #pragma unroll
      for (int d = 1; d < 16; d <<= 1) mv = fmaxf(mv, __shfl_xor(mv, d));
      mrow[ri][r] = mv;
      if (m16 == 0) wrow[w][row] = mv;
    }
  }
  __syncthreads();
  float ev[2][4][4];
  float dsum[2][4];
  #pragma unroll
  for (int ri = 0; ri < 2; ++ri){
    #pragma unroll
    for (int r = 0; r < 4; ++r){
      int row = ri*16 + q*4 + r;
      float m = fmaxf(fmaxf(wrow[0][row], wrow[1][row]), fmaxf(wrow[2][row], wrow[3][row]));
      mrow[ri][r] = m;
      dsum[ri][r] = 0.f;
      #pragma unroll
      for (int cj = 0; cj < 4; ++cj){
        float scol = sS[c0 + cj*16 + m16];
        float e = __expf(acc[ri][cj][r] - m);
        ev[ri][cj][r] = e;
        dsum[ri][r] = fmaf(e, scol, dsum[ri][r]);
      }
      #pragma unroll
      for (int d = 1; d < 16; d <<= 1) dsum[ri][r] += __shfl_xor(dsum[ri][r], d);
      if (m16 == 0) wden[w][row] = dsum[ri][r];
    }
  }
  __syncthreads();
  #pragma unroll
  for (int ri = 0; ri < 2; ++ri){
    #pragma unroll
    for (int r = 0; r < 4; ++r){
      int row = ri*16 + q*4 + r;
      float den = wden[0][row] + wden[1][row] + wden[2][row] + wden[3][row];
      float inv = 1.0f/den;
      #pragma unroll
      for (int cj = 0; cj < 4; ++cj){
        int col = c0 + cj*16 + m16;
        Eap[(size_t)(r0 + row)*256 + col] = f2bf(ev[ri][cj][r]*inv);
      }
    }
  }
}

// ---------------------------------------------------------------------------
// phiE: E = exp(phi - rowmax) fp32, mr = rowmax  (for Ep/Et used by k_emit)
__global__ __launch_bounds__(256) void k_phiE(const float* __restrict__ A,
    const unsigned short* __restrict__ projT, float* __restrict__ E,
    float* __restrict__ mr, int M)
{
  __shared__ float lnrm[32];
  __shared__ float wrow[4][32];
  int r0 = blockIdx.x*32;
  int tid = threadIdx.x;
  int w = tid >> 6, ln = tid & 63;
  int m16 = ln & 15, q = ln >> 4;
  f32x4 acc[2][4];
  #pragma unroll
  for (int i = 0; i < 2; ++i)
    #pragma unroll
    for (int jx = 0; jx < 4; ++jx) acc[i][jx] = (f32x4){0.f,0.f,0.f,0.f};
  phi_core(A, projT, r0, M, w, ln, acc, lnrm);
  __syncthreads();
  int c0 = w*64;
  #pragma unroll
  for (int ri = 0; ri < 2; ++ri){
    #pragma unroll
    for (int r = 0; r < 4; ++r){
      int row = ri*16 + q*4 + r;
      float mv = -1e30f;
      #pragma unroll
      for (int cj = 0; cj < 4; ++cj){
        acc[ri][cj][r] -= lnrm[row];
        mv = fmaxf(mv, acc[ri][cj][r]);
      }
      #pragma unroll
      for (int d = 1; d < 16; d <<= 1) mv = fmaxf(mv, __shfl_xor(mv, d));
      if (m16 == 0) wrow[w][row] = mv;
    }
  }
  __syncthreads();
  #pragma unroll
  for (int ri = 0; ri < 2; ++ri){
    #pragma unroll
    for (int r = 0; r < 4; ++r){
      int row = ri*16 + q*4 + r;
      int grow = r0 + row;
      float m = fmaxf(fmaxf(wrow[0][row], wrow[1][row]), fmaxf(wrow[2][row], wrow[3][row]));
      if (grow < M){
        #pragma unroll
        for (int cj = 0; cj < 4; ++cj){
          int col = c0 + cj*16 + m16;
          E[(size_t)grow*256 + col] = __expf(acc[ri][cj][r] - m);
        }
        if (w == 0 && m16 == 0) mr[grow] = m;
      }
    }
  }
}

// ---------------------------------------------------------------------------
// start vector: fx through 5 layers, then phi(fx) -> Eafx (normalized)
__global__ __launch_bounds__(256) void k_fx(
  const float* __restrict__ se, const float* __restrict__ sw, const float* __restrict__ sb,
  const float* __restrict__ proj, float* __restrict__ Eafx)
{
  __shared__ float xv[256], hv[256], red[4];
  int t = threadIdx.x;
  hv[t] = se[t];
  __syncthreads();
  float acc = sb[t];
  for (int h = 0; h < 256; ++h) acc = fmaf(hv[h], sw[h*256 + t], acc);
  __syncthreads();
  xv[t] = acc;
  __syncthreads();
  acc = sb[256 + t];
  for (int h = 0; h < 256; ++h) acc = fmaf(xv[h], sw[65536 + h*256 + t], acc);
  hv[t] = fmaxf(acc, 0.f);
  __syncthreads();
  acc = sb[512 + t];
  for (int h = 0; h < 256; ++h) acc = fmaf(hv[h], sw[2*65536 + h*256 + t], acc);
  float xnew = xv[t] + fmaxf(acc, 0.f);
  __syncthreads();
  xv[t] = xnew;
  __syncthreads();
  acc = sb[768 + t];
  for (int h = 0; h < 256; ++h) acc = fmaf(xv[h], sw[3*65536 + h*256 + t], acc);
  hv[t] = fmaxf(acc, 0.f);
  __syncthreads();
  acc = sb[1024 + t];
  for (int h = 0; h < 256; ++h) acc = fmaf(hv[h], sw[4*65536 + h*256 + t], acc);
  xnew = xv[t] + fmaxf(acc, 0.f);
  __syncthreads();
  xv[t] = xnew;
  __syncthreads();
  float v = xv[t]*xv[t];
  #pragma unroll
  for (int m = 1; m < 64; m <<= 1) v += __shfl_xor(v, m);
  if ((t & 63) == 0) red[t >> 6] = v;
  __syncthreads();
  float nx = red[0]+red[1]+red[2]+red[3];
  float px = -0.5f*nx;
  for (int h = 0; h < 256; ++h) px = fmaf(xv[h], proj[h*256 + t], px);
  __syncthreads();
  float m2 = px;
  #pragma unroll
  for (int m = 1; m < 64; m <<= 1) m2 = fmaxf(m2, __shfl_xor(m2, m));
  if ((t & 63) == 0) red[t >> 6] = m2;
  __syncthreads();
  m2 = fmaxf(fmaxf(red[0], red[1]), fmaxf(red[2], red[3]));
  Eafx[t] = __expf(px - m2);
}

// ---------------------------------------------------------------------------
__global__ void k_lists(const int* __restrict__ w2s, int* __restrict__ cnt, int* __restrict__ list){
  int v = blockIdx.x*256 + threadIdx.x;
  if (v < V_){
    int k = w2s[v*32] >> 5;
    int pos = atomicAdd(&cnt[k], 1);
    if (pos < CAP_) list[k*CAP_ + pos] = v;
  }
}

// ---------------------------------------------------------------------------
// per-cluster emit log-softmax: emit_col[v*32 + i] = emit_lp[k*32+i, v]
__global__ __launch_bounds__(256) void k_emit(
    const float* __restrict__ Ep, const float* __restrict__ mp,
    const float* __restrict__ Et, const float* __restrict__ mt,
    const int* __restrict__ cnt, const int* __restrict__ list,
    float* __restrict__ emit_col)
{
  __shared__ float Eps[32*260];
  __shared__ float lbuf[32*CAP_];
  __shared__ int   vls[CAP_];
  __shared__ float mps[32];
  int k = blockIdx.x, tid = threadIdx.x;
  for (int idx = tid; idx < 32*256; idx += 256){
    int i = idx >> 8, d = idx & 255;
    Eps[i*260 + d] = Ep[(size_t)(k*32 + i)*256 + d];
  }
  if (tid < 32) mps[tid] = mp[k*32 + tid];
  int n = cnt[k]; if (n > CAP_) n = CAP_;
  for (int w = tid; w < n; w += 256) vls[w] = list[k*CAP_ + w];
  __syncthreads();
  int i = tid >> 3, l = tid & 7;
  const float* Eprow = &Eps[i*260];
  float mpi = mps[i];
  float mrun = -1e30f, srun = 0.f;
  for (int w = 0; w < n; ++w){
    int v = vls[w];
    const float* etr = Et + (size_t)v*256;
    float dot = 0.f;
    #pragma unroll
    for (int g = 0; g < 32; ++g){
      int d = g*8 + l;
      dot = fmaf(Eprow[d], etr[d], dot);
    }
    dot += __shfl_xor(dot, 1);
    dot += __shfl_xor(dot, 2);
    dot += __shfl_xor(dot, 4);
    float logit = __logf(dot) + mpi + mt[v];
    float nm = fmaxf(mrun, logit);
    srun = srun*__expf(mrun - nm) + __expf(logit - nm);
    mrun = nm;
    if (l == 0) lbuf[i*CAP_ + w] = logit;
  }
  float den = mrun + __logf(srun);
  __syncthreads();
  for (int w = l; w < n; w += 8){
    emit_col[(size_t)vls[w]*32 + i] = lbuf[i*CAP_ + w] - den;
  }
}

// ---------------------------------------------------------------------------
// 32x32 product helpers (tree reduction)
__device__ inline void wave_norm_store(f32x4 acc[2][2], float* outp, int ostride,
                                       float sIn, float* sOut, int ln)
{
  int m16 = ln & 15, q = ln >> 4;
  float mx = 0.f;
  #pragma unroll
  for (int mi = 0; mi < 2; ++mi)
    #pragma unroll
    for (int ni = 0; ni < 2; ++ni)
      #pragma unroll
      for (int r = 0; r < 4; ++r) mx = fmaxf(mx, acc[mi][ni][r]);
  #pragma unroll
  for (int d = 1; d < 64; d <<= 1) mx = fmaxf(mx, __shfl_xor(mx, d));
  float inv = 1.0f/mx;
  #pragma unroll
  for (int mi = 0; mi < 2; ++mi)
    #pragma unroll
    for (int ni = 0; ni < 2; ++ni)
      #pragma unroll
      for (int r = 0; r < 4; ++r)
        outp[(mi*16 + q*4 + r)*ostride + ni*16 + m16] = acc[mi][ni][r]*inv;
  if (ln == 0) *sOut = sIn + __logf(mx);
}

__device__ inline void prod32(const float* L0, const float* L1, float* outp, int ostride,
                              float sIn, float* sOut, int ln)
{
  int m16 = ln & 15, q = ln >> 4;
  bf16x8 af[2], bfv[2];
  #pragma unroll
  for (int mi = 0; mi < 2; ++mi){
    const float* p = L0 + (mi*16 + m16)*MST + q*8;
    u16x8 u;
    #pragma unroll
    for (int jj = 0; jj < 8; ++jj) u[jj] = f2bf(p[jj]);
    af[mi] = __builtin_bit_cast(bf16x8, u);
  }
  #pragma unroll
  for (int ni = 0; ni < 2; ++ni){
    u16x8 u;
    #pragma unroll
    for (int jj = 0; jj < 8; ++jj) u[jj] = f2bf(L1[(q*8 + jj)*MST + ni*16 + m16]);
    bfv[ni] = __builtin_bit_cast(bf16x8, u);
  }
  f32x4 acc[2][2];
  #pragma unroll
  for (int mi = 0; mi < 2; ++mi)
    #pragma unroll
    for (int ni = 0; ni < 2; ++ni) acc[mi][ni] = (f32x4){0.f,0.f,0.f,0.f};
  #pragma unroll
  for (int mi = 0; mi < 2; ++mi)
    #pragma unroll
    for (int ni = 0; ni < 2; ++ni) acc[mi][ni] = mfma16(af[mi], bfv[ni], acc[mi][ni]);
  wave_norm_store(acc, outp, ostride, sIn, sOut, ln);
}

// ---------------------------------------------------------------------------
// k_chunk: one workgroup per (batch, chunk of 16 time-steps).
// Builds 16 leaf matrices M_t = P_t * diag(e_t) (normalized, log-scale) and
// reduces them to one 32x32 product in LDS. 256 workgroups x 8 waves.
__global__ __launch_bounds__(512) void k_chunk(
  const unsigned short* __restrict__ Eap, const unsigned short* __restrict__ Ebp,
  const float* __restrict__ emit_col, const int* __restrict__ text,
  const int* __restrict__ w2s, float* __restrict__ Gm, float* __restrict__ Gs)
{
  __shared__ float bufL[16][32*MST];
  __shared__ float bufP[8][32*MST];
  __shared__ float sL[16], sA[8], sB[4], sC[2];
  int bc = blockIdx.x;
  int b = bc >> 4, ch = bc & 15;
  int w = threadIdx.x >> 6, ln = threadIdx.x & 63;
  int m16 = ln & 15, q = ln >> 4;
  // phase 1: leaves 2w, 2w+1
  for (int u = 0; u < 2; ++u){
    int l = 2*w + u;
    int s = ch*16 + l;          // leaf s corresponds to transition step t = s+1
    float* outp = bufL[l];
    if (s >= 255){
      for (int i = ln; i < 32*32; i += 64){
        int r = i >> 5, c = i & 31;
        outp[r*MST + c] = (r == c) ? 1.f : 0.f;
      }
      if (ln == 0) sL[l] = 0.f;
    } else {
      int vp = text[b*256 + s], vc = text[b*256 + s + 1];
      int bp = w2s[vp*32], bq = w2s[vc*32];
      const unsigned short* a0 = Eap + (size_t)(bp + m16)*256 + q*8;
      const unsigned short* b0 = Ebp + (size_t)(bq + m16)*256 + q*8;
      f32x4 acc[2][2];
      #pragma unroll
      for (int mi = 0; mi < 2; ++mi)
        #pragma unroll
        for (int ni = 0; ni < 2; ++ni) acc[mi][ni] = (f32x4){0.f,0.f,0.f,0.f};
      #pragma unroll
      for (int kt = 0; kt < 8; ++kt){
        bf16x8 a_0 = *(const bf16x8*)(a0 + kt*32);
        bf16x8 a_1 = *(const bf16x8*)(a0 + 16*256 + kt*32);
        bf16x8 b_0 = *(const bf16x8*)(b0 + kt*32);
        bf16x8 b_1 = *(const bf16x8*)(b0 + 16*256 + kt*32);
        acc[0][0] = mfma16(a_0, b_0, acc[0][0]);
        acc[0][1] = mfma16(a_0, b_1, acc[0][1]);
        acc[1][0] = mfma16(a_1, b_0, acc[1][0]);
        acc[1][1] = mfma16(a_1, b_1, acc[1][1]);
      }
      float e0 = __expf(emit_col[(size_t)vc*32 + m16]);
      float e1 = __expf(emit_col[(size_t)vc*32 + 16 + m16]);
      #pragma unroll
      for (int mi = 0; mi < 2; ++mi)
        #pragma unroll
        for (int r = 0; r < 4; ++r){
          acc[mi][0][r] *= e0;
          acc[mi][1][r] *= e1;
        }
      wave_norm_store(acc, outp, MST, 0.f, &sL[l], ln);
    }
  }
  __syncthreads();
  prod32(bufL[2*w], bufL[2*w+1], bufP[w], MST, sL[2*w] + sL[2*w+1], &sA[w], ln);
  __syncthreads();
  if (w < 4) prod32(bufP[2*w], bufP[2*w+1], bufL[w], MST, sA[2*w] + sA[2*w+1], &sB[w], ln);
  __syncthreads();
  if (w < 2) prod32(bufL[2*w], bufL[2*w+1], bufP[w], MST, sB[2*w] + sB[2*w+1], &sC[w], ln);
  __syncthreads();
  if (w == 0) prod32(bufP[0], bufP[1], Gm + (size_t)bc*1024, 32, sC[0] + sC[1], Gs + bc, ln);
}

// ---------------------------------------------------------------------------
// k_root: per batch, reduce the 16 chunk matrices, then contract with alpha0.
// alpha0 computed analytically: start_lp[c] = log(Eafx.Ebp[c]) - log(Eafx.S)
__global__ __launch_bounds__(512) void k_root(
  const float* __restrict__ Gm, const float* __restrict__ Gs,
  const float* __restrict__ Eafx, const float* __restrict__ S,
  const unsigned short* __restrict__ Ebp, const float* __restrict__ emit_col,
  const int* __restrict__ text, const int* __restrict__ w2s, float* __restrict__ out)
{
  __shared__ float bufL[16][32*MST];
  __shared__ float bufP[8][32*MST];
  __shared__ float sL[16], sA[8], sB[4], sC[2], sD[1];
  int b = blockIdx.x;
  int w = threadIdx.x >> 6, ln = threadIdx.x & 63;
  for (int idx = threadIdx.x; idx < 16*1024; idx += 512){
    int i = idx >> 10, e = idx & 1023;
    bufL[i][(e >> 5)*MST + (e & 31)] = Gm[(size_t)(b*16 + i)*1024 + e];
  }
  if (threadIdx.x < 16) sL[threadIdx.x] = Gs[b*16 + threadIdx.x];
  __syncthreads();
  prod32(bufL[2*w], bufL[2*w+1], bufP[w], MST, sL[2*w] + sL[2*w+1], &sA[w], ln);
  __syncthreads();
  if (w < 4) prod32(bufP[2*w], bufP[2*w+1], bufL[w], MST, sA[2*w] + sA[2*w+1], &sB[w], ln);
  __syncthreads();
  if (w < 2) prod32(bufL[2*w], bufL[2*w+1], bufP[w], MST, sB[2*w] + sB[2*w+1], &sC[w], ln);
  __syncthreads();
  if (w == 0){
    prod32(bufP[0], bufP[1], bufL[0], MST, sC[0] + sC[1], &sD[0], ln);
    // dfx = Eafx . S
    float part = 0.f;
    for (int d = ln; d < 256; d += 64) part = fmaf(Eafx[d], S[d], part);
    #pragma unroll
    for (int d2 = 1; d2 < 64; d2 <<= 1) part += __shfl_xor(part, d2);
    float dfx = part;
    int v0 = text[b*256];
    int k0 = w2s[v0*32];
    int j = ln & 31, h = ln >> 5;
    const unsigned short* er = Ebp + (size_t)(k0 + j)*256;
    float dot = 0.f;
    for (int d = h*128; d < h*128 + 128; ++d)
      dot = fmaf(Eafx[d], bf2f(er[d]), dot);
    dot += __shfl_xor(dot, 32);
    float z0 = __logf(dot) + emit_col[(size_t)v0*32 + j];
    float mz = z0;
    #pragma unroll
    for (int d2 = 1; d2 < 32; d2 <<= 1) mz = fmaxf(mz, __shfl_xor(mz, d2));
    float an = __expf(z0 - mz);
    float cs = 0.f;
    for (int i = h*16; i < h*16 + 16; ++i)
      cs = fmaf(__shfl(an, i), bufL[0][i*MST + j], cs);
    cs += __shfl_xor(cs, 32);
    float tot = cs;
    #pragma unroll
    for (int d2 = 1; d2 < 32; d2 <<= 1) tot += __shfl_xor(tot, d2);
    if (ln == 0) out[b] = __logf(tot) + mz + sD[0] - __logf(dfx);
  }
}

// ---------------------------------------------------------------------------
extern "C" void kernel_launch(void* const* d_in, const int* in_sizes, int n_in,
                              void* d_out, int out_size, void* d_ws, size_t ws_size,
                              hipStream_t stream)
{
  (void)in_sizes; (void)n_in; (void)out_size; (void)ws_size;
  const int*   text      = (const int*)  d_in[0];
  const float* start_emb = (const float*)d_in[1];
  const float* start_w   = (const float*)d_in[2];
  const float* start_b   = (const float*)d_in[3];
  const float* state_emb = (const float*)d_in[4];
  const float* next_emb  = (const float*)d_in[5];
  const float* pre_emb   = (const float*)d_in[6];
  const float* term_w    = (const float*)d_in[7];
  const float* term_b    = (const float*)d_in[8];
  const float* term_emb  = (const float*)d_in[9];
  const float* proj      = (const float*)d_in[10];
  const int*   w2s       = (const int*)  d_in[11];
  float* out = (float*)d_out;

  char* base = (char*)d_ws;
  size_t off = 0;
  auto alloc = [&](size_t bytes)->char*{
    char* p = base + off;
    off += (bytes + 255) & ~(size_t)255;
    return p;
  };
  unsigned short* projT = (unsigned short*)alloc((size_t)65536*2);
  unsigned short* WT    = (unsigned short*)alloc((size_t)4*65536*2);
  float* Eafx = (float*)alloc(256*4);
  float* H1   = (float*)alloc((size_t)C_*256*4);   // h1 / h3
  float* X2   = (float*)alloc((size_t)C_*256*4);
  float* FP   = (float*)alloc((size_t)C_*256*4);
  float* Ep   = (float*)alloc((size_t)C_*256*4);
  float* mpp  = (float*)alloc((size_t)C_*4);
  float* Et   = (float*)alloc((size_t)V_*256*4);
  float* mt   = (float*)alloc((size_t)V_*4);
  float* S    = (float*)alloc(256*4);
  unsigned short* Eap = (unsigned short*)alloc((size_t)C_*256*2);
  unsigned short* Ebp = (unsigned short*)alloc((size_t)C_*256*2);
  int* cnt  = (int*)alloc(128*4);
  int* list = (int*)alloc((size_t)128*CAP_*4);
  float* emit_col = (float*)alloc((size_t)V_*32*4);
  float* Gm = (float*)alloc((size_t)256*1024*4);
  float* Gs = (float*)alloc((size_t)256*4);

  hipMemsetAsync(S, 0, 256*4, stream);
  hipMemsetAsync(cnt, 0, 128*4, stream);

  k_tpack<<<dim3(256,5), 256, 0, stream>>>(proj, term_w, projT, WT);
  k_lists<<<40, 256, 0, stream>>>(w2s, cnt, list);
  k_fx<<<1, 256, 0, stream>>>(start_emb, start_w, start_b, proj, Eafx);

  // preterminal MLP (4 fused layers)
  k_mlp<<<128, 256, 0, stream>>>(pre_emb, WT + 0*65536, term_b + 0,   nullptr, H1);
  k_mlp<<<128, 256, 0, stream>>>(H1,      WT + 1*65536, term_b + 256, pre_emb, X2);
  k_mlp<<<128, 256, 0, stream>>>(X2,      WT + 2*65536, term_b + 512, nullptr, H1);
  k_mlp<<<128, 256, 0, stream>>>(H1,      WT + 3*65536, term_b + 768, X2,      FP);

  // phi kernels (fused pack+gemm+epilogue)
  k_phiB<<<128, 256, 0, stream>>>(next_emb, projT, Ebp, S);
  k_phiA<<<128, 256, 0, stream>>>(state_emb, projT, S, Eap);
  k_phiE<<<313, 256, 0, stream>>>(term_emb, projT, Et, mt, V_);
  k_phiE<<<128, 256, 0, stream>>>(FP, projT, Ep, mpp, C_);

  k_emit<<<128, 256, 0, stream>>>(Ep, mpp, Et, mt, cnt, list, emit_col);

  // tree reduction over transition-emission matrices
  k_chunk<<<256, 512, 0, stream>>>(Eap, Ebp, emit_col, text, w2s, Gm, Gs);
  k_root<<<16, 512, 0, stream>>>(Gm, Gs, Eafx, S, Ebp, emit_col, text, w2s, out);
}

// Round 3
// 272.916 us; speedup vs baseline: 1.9768x; 1.3219x over previous
//
#include <hip/hip_runtime.h>

#define B_   16
#define T_   256
#define V_   10000
#define C_   4096
#define H_   256
#define NC_  128
#define CAP_ 224
#define MST  33   // LDS matrix stride (32 + 1 pad)

typedef __bf16 bf16x8 __attribute__((ext_vector_type(8)));
typedef unsigned short u16x8 __attribute__((ext_vector_type(8)));
typedef float  f32x4  __attribute__((ext_vector_type(4)));

__device__ inline unsigned short f2bf(float f){
  unsigned int u = __float_as_uint(f);
  u += 0x7FFFu + ((u >> 16) & 1u);
  return (unsigned short)(u >> 16);
}
__device__ inline float bf2f(unsigned short u){
  return __uint_as_float(((unsigned int)u) << 16);
}
__device__ inline f32x4 mfma16(bf16x8 a, bf16x8 b, f32x4 c){
  return __builtin_amdgcn_mfma_f32_16x16x32_bf16(a, b, c, 0, 0, 0);
}
__device__ inline bf16x8 load_cvt8(const float* p){
  u16x8 u;
  #pragma unroll
  for (int i = 0; i < 8; ++i) u[i] = f2bf(p[i]);
  return __builtin_bit_cast(bf16x8, u);
}

// ---------------------------------------------------------------------------
// Transpose-pack projection (z=0) and terminal_w[0..3] (z=1..4) into bf16 NxK
__global__ void k_tpack(const float* __restrict__ proj, const float* __restrict__ tw,
                        unsigned short* __restrict__ projT, unsigned short* __restrict__ WT){
  int z = blockIdx.y;
  int dcol = blockIdx.x;
  int h = threadIdx.x;
  const float* src = (z == 0) ? proj : (tw + (size_t)(z-1)*65536);
  unsigned short* dst = (z == 0) ? projT : (WT + (size_t)(z-1)*65536);
  dst[dcol*256 + h] = f2bf(src[h*256 + dcol]);
}

// ---------------------------------------------------------------------------
// Fused MLP layer: C = res + relu(A @ Bt^T + bias), A fp32 converted in-register
__global__ __launch_bounds__(256) void k_mlp(const float* __restrict__ A,
    const unsigned short* __restrict__ Bt, const float* __restrict__ bias,
    const float* __restrict__ res, float* __restrict__ C)
{
  int r0 = blockIdx.x*32;
  int tid = threadIdx.x;
  int w = tid >> 6, ln = tid & 63;
  int m16 = ln & 15, q = ln >> 4;
  int c0 = w*64;
  const float* a0 = A + (size_t)(r0 + m16)*256 + q*8;
  const float* a1 = a0 + 16*256;
  const unsigned short* bp0 = Bt + (size_t)(c0 + m16)*256 + q*8;
  f32x4 acc[2][4];
  #pragma unroll
  for (int i = 0; i < 2; ++i)
    #pragma unroll
    for (int jx = 0; jx < 4; ++jx) acc[i][jx] = (f32x4){0.f,0.f,0.f,0.f};
  #pragma unroll
  for (int kt = 0; kt < 8; ++kt){
    bf16x8 af0 = load_cvt8(a0 + kt*32);
    bf16x8 af1 = load_cvt8(a1 + kt*32);
    #pragma unroll
    for (int cj = 0; cj < 4; ++cj){
      bf16x8 bfj = *(const bf16x8*)(bp0 + (size_t)cj*16*256 + kt*32);
      acc[0][cj] = mfma16(af0, bfj, acc[0][cj]);
      acc[1][cj] = mfma16(af1, bfj, acc[1][cj]);
    }
  }
  #pragma unroll
  for (int ri = 0; ri < 2; ++ri){
    #pragma unroll
    for (int cj = 0; cj < 4; ++cj){
      #pragma unroll
      for (int r = 0; r < 4; ++r){
        int row = r0 + ri*16 + q*4 + r;
        int col = c0 + cj*16 + m16;
        float v = acc[ri][cj][r] + bias[col];
        v = fmaxf(v, 0.f);
        if (res) v += res[(size_t)row*256 + col];
        C[(size_t)row*256 + col] = v;
      }
    }
  }
}

// ---------------------------------------------------------------------------
// phi GEMM core: 32-row slab x full 256 cols, A fp32 cvt in-register.
// Also computes 0.5*||row||^2 into lnrm (wave 0).
__device__ inline void phi_core(const float* __restrict__ A,
    const unsigned short* __restrict__ Bt, int r0, int M, int w, int ln,
    f32x4 acc[2][4], float* lnrm)
{
  int m16 = ln & 15, q = ln >> 4;
  int c0 = w*64;
  int ra0 = r0 + m16;      if (ra0 > M-1) ra0 = M-1;
  int ra1 = r0 + 16 + m16; if (ra1 > M-1) ra1 = M-1;
  const float* a0 = A + (size_t)ra0*256 + q*8;
  const float* a1 = A + (size_t)ra1*256 + q*8;
  const unsigned short* bp0 = Bt + (size_t)(c0 + m16)*256 + q*8;
  float ss0 = 0.f, ss1 = 0.f;
  #pragma unroll
  for (int kt = 0; kt < 8; ++kt){
    float av0[8], av1[8];
    #pragma unroll
    for (int i2 = 0; i2 < 8; ++i2){ av0[i2] = a0[kt*32 + i2]; av1[i2] = a1[kt*32 + i2]; }
    u16x8 u0, u1;
    #pragma unroll
    for (int i2 = 0; i2 < 8; ++i2){
      u0[i2] = f2bf(av0[i2]); u1[i2] = f2bf(av1[i2]);
      ss0 = fmaf(av0[i2], av0[i2], ss0);
      ss1 = fmaf(av1[i2], av1[i2], ss1);
    }
    bf16x8 af0 = __builtin_bit_cast(bf16x8, u0);
    bf16x8 af1 = __builtin_bit_cast(bf16x8, u1);
    #pragma unroll
    for (int cj = 0; cj < 4; ++cj){
      bf16x8 bfj = *(const bf16x8*)(bp0 + (size_t)cj*16*256 + kt*32);
      acc[0][cj] = mfma16(af0, bfj, acc[0][cj]);
      acc[1][cj] = mfma16(af1, bfj, acc[1][cj]);
    }
  }
  ss0 += __shfl_xor(ss0, 16); ss0 += __shfl_xor(ss0, 32);
  ss1 += __shfl_xor(ss1, 16); ss1 += __shfl_xor(ss1, 32);
  if (w == 0 && q == 0){ lnrm[m16] = 0.5f*ss0; lnrm[16 + m16] = 0.5f*ss1; }
}

// ---------------------------------------------------------------------------
// phiB: Ebp = bf16(exp(phi))  (= Eb * e^{mb}), S[d] += column sums (atomic)
__global__ __launch_bounds__(256) void k_phiB(const float* __restrict__ A,
    const unsigned short* __restrict__ projT, unsigned short* __restrict__ Ebp,
    float* __restrict__ S)
{
  __shared__ float lnrm[32];
  int r0 = blockIdx.x*32;
  int tid = threadIdx.x;
  int w = tid >> 6, ln = tid & 63;
  int m16 = ln & 15, q = ln >> 4;
  f32x4 acc[2][4];
  #pragma unroll
  for (int i = 0; i < 2; ++i)
    #pragma unroll
    for (int jx = 0; jx < 4; ++jx) acc[i][jx] = (f32x4){0.f,0.f,0.f,0.f};
  phi_core(A, projT, r0, C_, w, ln, acc, lnrm);
  __syncthreads();
  int c0 = w*64;
  #pragma unroll
  for (int cj = 0; cj < 4; ++cj){
    int col = c0 + cj*16 + m16;
    float cs = 0.f;
    #pragma unroll
    for (int ri = 0; ri < 2; ++ri){
      #pragma unroll
      for (int r = 0; r < 4; ++r){
        int row = ri*16 + q*4 + r;
        float e = __expf(acc[ri][cj][r] - lnrm[row]);
        Ebp[(size_t)(r0 + row)*256 + col] = f2bf(e);
        cs += e;
      }
    }
    cs += __shfl_xor(cs, 16); cs += __shfl_xor(cs, 32);
    if (q == 0) atomicAdd(&S[col], cs);
  }
}

// ---------------------------------------------------------------------------
// phiA: Eap = bf16( exp(phi - m) / sum_d exp(phi-m)*S[d] )
__global__ __launch_bounds__(256) void k_phiA(const float* __restrict__ A,
    const unsigned short* __restrict__ projT, const float* __restrict__ S,
    unsigned short* __restrict__ Eap)
{
  __shared__ float lnrm[32];
  __shared__ float sS[256];
  __shared__ float wrow[4][32];
  __shared__ float wden[4][32];
  int r0 = blockIdx.x*32;
  int tid = threadIdx.x;
  int w = tid >> 6, ln = tid & 63;
  int m16 = ln & 15, q = ln >> 4;
  sS[tid] = S[tid];
  f32x4 acc[2][4];
  #pragma unroll
  for (int i = 0; i < 2; ++i)
    #pragma unroll
    for (int jx = 0; jx < 4; ++jx) acc[i][jx] = (f32x4){0.f,0.f,0.f,0.f};
  phi_core(A, projT, r0, C_, w, ln, acc, lnrm);
  __syncthreads();
  int c0 = w*64;
  #pragma unroll
  for (int ri = 0; ri < 2; ++ri){
    #pragma unroll
    for (int r = 0; r < 4; ++r){
      int row = ri*16 + q*4 + r;
      float mv = -1e30f;
      #pragma unroll
      for (int cj = 0; cj < 4; ++cj){
        acc[ri][cj][r] -= lnrm[row];
        mv = fmaxf(mv, acc[ri][cj][r]);
      }
      #pragma unroll
      for (int d = 1; d < 16; d <<= 1) mv = fmaxf(mv, __shfl_xor(mv, d));
      if (m16 == 0) wrow[w][row] = mv;
    }
  }
  __syncthreads();
  float ev[2][4][4];
  float dsum[2][4];
  #pragma unroll
  for (int ri = 0; ri < 2; ++ri){
    #pragma unroll
    for (int r = 0; r < 4; ++r){
      int row = ri*16 + q*4 + r;
      float m = fmaxf(fmaxf(wrow[0][row], wrow[1][row]), fmaxf(wrow[2][row], wrow[3][row]));
      dsum[ri][r] = 0.f;
      #pragma unroll
      for (int cj = 0; cj < 4; ++cj){
        float scol = sS[c0 + cj*16 + m16];
        float e = __expf(acc[ri][cj][r] - m);
        ev[ri][cj][r] = e;
        dsum[ri][r] = fmaf(e, scol, dsum[ri][r]);
      }
      #pragma unroll
      for (int d = 1; d < 16; d <<= 1) dsum[ri][r] += __shfl_xor(dsum[ri][r], d);
      if (m16 == 0) wden[w][row] = dsum[ri][r];
    }
  }
  __syncthreads();
  #pragma unroll
  for (int ri = 0; ri < 2; ++ri){
    #pragma unroll
    for (int r = 0; r < 4; ++r){
      int row = ri*16 + q*4 + r;
      float den = wden[0][row] + wden[1][row] + wden[2][row] + wden[3][row];
      float inv = 1.0f/den;
      #pragma unroll
      for (int cj = 0; cj < 4; ++cj){
        int col = c0 + cj*16 + m16;
        Eap[(size_t)(r0 + row)*256 + col] = f2bf(ev[ri][cj][r]*inv);
      }
    }
  }
}

// ---------------------------------------------------------------------------
// phiE: E = bf16(exp(phi - rowmax)), mr = rowmax  (for Ep/Et used by k_emit)
__global__ __launch_bounds__(256) void k_phiE(const float* __restrict__ A,
    const unsigned short* __restrict__ projT, unsigned short* __restrict__ E,
    float* __restrict__ mr, int M)
{
  __shared__ float lnrm[32];
  __shared__ float wrow[4][32];
  int r0 = blockIdx.x*32;
  int tid = threadIdx.x;
  int w = tid >> 6, ln = tid & 63;
  int m16 = ln & 15, q = ln >> 4;
  f32x4 acc[2][4];
  #pragma unroll
  for (int i = 0; i < 2; ++i)
    #pragma unroll
    for (int jx = 0; jx < 4; ++jx) acc[i][jx] = (f32x4){0.f,0.f,0.f,0.f};
  phi_core(A, projT, r0, M, w, ln, acc, lnrm);
  __syncthreads();
  int c0 = w*64;
  #pragma unroll
  for (int ri = 0; ri < 2; ++ri){
    #pragma unroll
    for (int r = 0; r < 4; ++r){
      int row = ri*16 + q*4 + r;
      float mv = -1e30f;
      #pragma unroll
      for (int cj = 0; cj < 4; ++cj){
        acc[ri][cj][r] -= lnrm[row];
        mv = fmaxf(mv, acc[ri][cj][r]);
      }
      #pragma unroll
      for (int d = 1; d < 16; d <<= 1) mv = fmaxf(mv, __shfl_xor(mv, d));
      if (m16 == 0) wrow[w][row] = mv;
    }
  }
  __syncthreads();
  #pragma unroll
  for (int ri = 0; ri < 2; ++ri){
    #pragma unroll
    for (int r = 0; r < 4; ++r){
      int row = ri*16 + q*4 + r;
      int grow = r0 + row;
      float m = fmaxf(fmaxf(wrow[0][row], wrow[1][row]), fmaxf(wrow[2][row], wrow[3][row]));
      if (grow < M){
        #pragma unroll
        for (int cj = 0; cj < 4; ++cj){
          int col = c0 + cj*16 + m16;
          E[(size_t)grow*256 + col] = f2bf(__expf(acc[ri][cj][r] - m));
        }
        if (w == 0 && m16 == 0) mr[grow] = m;
      }
    }
  }
}

// ---------------------------------------------------------------------------
// start vector: fx through 5 layers, then phi(fx) -> Eafx (normalized).
// 1024 threads: (u,t), u in [0,4) = partial over h in [64u, 64u+64)
__global__ __launch_bounds__(1024) void k_fx(
  const float* __restrict__ se, const float* __restrict__ sw, const float* __restrict__ sb,
  const float* __restrict__ proj, float* __restrict__ Eafx)
{
  __shared__ float xv[256], hv[256];
  __shared__ float part[4][256];
  __shared__ float red[4];
  int tid = threadIdx.x;
  int t = tid & 255, u = tid >> 8;
  if (u == 0) hv[t] = se[t];
  __syncthreads();
  // L0: xv = hv @ w0 + b0
  {
    const float* wp = sw + (size_t)(u*64)*256 + t;
    float a = 0.f;
    #pragma unroll 8
    for (int h = 0; h < 64; ++h) a = fmaf(hv[u*64 + h], wp[(size_t)h*256], a);
    part[u][t] = a;
  }
  __syncthreads();
  if (u == 0) xv[t] = part[0][t]+part[1][t]+part[2][t]+part[3][t] + sb[t];
  __syncthreads();
  // L1: hv = relu(xv @ w1 + b1)
  {
    const float* wp = sw + 65536 + (size_t)(u*64)*256 + t;
    float a = 0.f;
    #pragma unroll 8
    for (int h = 0; h < 64; ++h) a = fmaf(xv[u*64 + h], wp[(size_t)h*256], a);
    part[u][t] = a;
  }
  __syncthreads();
  if (u == 0) hv[t] = fmaxf(part[0][t]+part[1][t]+part[2][t]+part[3][t] + sb[256 + t], 0.f);
  __syncthreads();
  // L2: xv += relu(hv @ w2 + b2)
  {
    const float* wp = sw + 2*65536 + (size_t)(u*64)*256 + t;
    float a = 0.f;
    #pragma unroll 8
    for (int h = 0; h < 64; ++h) a = fmaf(hv[u*64 + h], wp[(size_t)h*256], a);
    part[u][t] = a;
  }
  __syncthreads();
  if (u == 0) xv[t] += fmaxf(part[0][t]+part[1][t]+part[2][t]+part[3][t] + sb[512 + t], 0.f);
  __syncthreads();
  // L3: hv = relu(xv @ w3 + b3)
  {
    const float* wp = sw + 3*65536 + (size_t)(u*64)*256 + t;
    float a = 0.f;
    #pragma unroll 8
    for (int h = 0; h < 64; ++h) a = fmaf(xv[u*64 + h], wp[(size_t)h*256], a);
    part[u][t] = a;
  }
  __syncthreads();
  if (u == 0) hv[t] = fmaxf(part[0][t]+part[1][t]+part[2][t]+part[3][t] + sb[768 + t], 0.f);
  __syncthreads();
  // L4: xv += relu(hv @ w4 + b4)
  {
    const float* wp = sw + 4*65536 + (size_t)(u*64)*256 + t;
    float a = 0.f;
    #pragma unroll 8
    for (int h = 0; h < 64; ++h) a = fmaf(hv[u*64 + h], wp[(size_t)h*256], a);
    part[u][t] = a;
  }
  __syncthreads();
  if (u == 0) xv[t] += fmaxf(part[0][t]+part[1][t]+part[2][t]+part[3][t] + sb[1024 + t], 0.f);
  __syncthreads();
  // nx = ||xv||^2
  if (u == 0){
    float v = xv[t]*xv[t];
    #pragma unroll
    for (int m = 1; m < 64; m <<= 1) v += __shfl_xor(v, m);
    if ((t & 63) == 0) red[t >> 6] = v;
  }
  __syncthreads();
  float nx = red[0]+red[1]+red[2]+red[3];
  // px = xv @ proj - 0.5*nx
  {
    const float* pp = proj + (size_t)(u*64)*256 + t;
    float a = 0.f;
    #pragma unroll 8
    for (int h = 0; h < 64; ++h) a = fmaf(xv[u*64 + h], pp[(size_t)h*256], a);
    part[u][t] = a;
  }
  __syncthreads();
  if (u == 0) hv[t] = part[0][t]+part[1][t]+part[2][t]+part[3][t] - 0.5f*nx;
  __syncthreads();
  if (u == 0){
    float m2 = hv[t];
    #pragma unroll
    for (int m = 1; m < 64; m <<= 1) m2 = fmaxf(m2, __shfl_xor(m2, m));
    if ((t & 63) == 0) red[t >> 6] = m2;
  }
  __syncthreads();
  if (u == 0){
    float m2 = fmaxf(fmaxf(red[0], red[1]), fmaxf(red[2], red[3]));
    Eafx[t] = __expf(hv[t] - m2);
  }
}

// ---------------------------------------------------------------------------
__global__ void k_lists(const int* __restrict__ w2s, int* __restrict__ cnt, int* __restrict__ list){
  int v = blockIdx.x*256 + threadIdx.x;
  if (v < V_){
    int k = w2s[v*32] >> 5;
    int pos = atomicAdd(&cnt[k], 1);
    if (pos < CAP_) list[k*CAP_ + pos] = v;
  }
}

// ---------------------------------------------------------------------------
// per-cluster emit log-softmax via MFMA:
// logits[32 x n] = log(Ep[k] @ Et[words]^T) + mp_i + mt_v; row-lse; scatter.
__global__ __launch_bounds__(256) void k_emit(
    const unsigned short* __restrict__ Epb, const float* __restrict__ mp,
    const unsigned short* __restrict__ Etb, const float* __restrict__ mt,
    const int* __restrict__ cnt, const int* __restrict__ list,
    float* __restrict__ emit_col)
{
  __shared__ float mtile[8][32];
  __shared__ float stile[8][32];
  __shared__ float mpl[32];
  __shared__ float denl[32];
  int k = blockIdx.x, tid = threadIdx.x;
  int w = tid >> 6, ln = tid & 63;
  int m16 = ln & 15, q = ln >> 4;
  if (tid < 32) mpl[tid] = mp[k*32 + tid];
  int n = cnt[k]; if (n > CAP_) n = CAP_;
  int nt = (n + 31) >> 5;
  const int* lp = list + k*CAP_;
  // A fragments (32 Ep rows, shared across tiles)
  bf16x8 af0[8], af1[8];
  {
    const unsigned short* ap0 = Epb + (size_t)(k*32 + m16)*256 + q*8;
    const unsigned short* ap1 = ap0 + 16*256;
    #pragma unroll
    for (int kt = 0; kt < 8; ++kt){
      af0[kt] = *(const bf16x8*)(ap0 + kt*32);
      af1[kt] = *(const bf16x8*)(ap1 + kt*32);
    }
  }
  float lg[2][2][2][4];   // [u][mi][ni][r]
  int   vj[2][2];
  #pragma unroll
  for (int u = 0; u < 2; ++u){
    int t = w + u*4;
    if (t >= nt) continue;
    int j0 = t*32 + m16, j1 = j0 + 16;
    int v0 = lp[(j0 < n) ? j0 : 0];
    int v1 = lp[(j1 < n) ? j1 : 0];
    vj[u][0] = v0; vj[u][1] = v1;
    float mt0 = (j0 < n) ? mt[v0] : 0.f;
    float mt1 = (j1 < n) ? mt[v1] : 0.f;
    const unsigned short* bp0 = Etb + (size_t)v0*256 + q*8;
    const unsigned short* bp1 = Etb + (size_t)v1*256 + q*8;
    f32x4 acc[2][2];
    #pragma unroll
    for (int mi = 0; mi < 2; ++mi)
      #pragma unroll
      for (int ni = 0; ni < 2; ++ni) acc[mi][ni] = (f32x4){0.f,0.f,0.f,0.f};
    #pragma unroll
    for (int kt = 0; kt < 8; ++kt){
      bf16x8 b0 = *(const bf16x8*)(bp0 + kt*32);
      bf16x8 b1 = *(const bf16x8*)(bp1 + kt*32);
      acc[0][0] = mfma16(af0[kt], b0, acc[0][0]);
      acc[0][1] = mfma16(af0[kt], b1, acc[0][1]);
      acc[1][0] = mfma16(af1[kt], b0, acc[1][0]);
      acc[1][1] = mfma16(af1[kt], b1, acc[1][1]);
    }
    // logits
    #pragma unroll
    for (int mi = 0; mi < 2; ++mi){
      #pragma unroll
      for (int r = 0; r < 4; ++r){
        int row = mi*16 + q*4 + r;
        float l0 = (j0 < n) ? (__logf(acc[mi][0][r]) + mpl[row] + mt0) : -1e30f;
        float l1 = (j1 < n) ? (__logf(acc[mi][1][r]) + mpl[row] + mt1) : -1e30f;
        lg[u][mi][0][r] = l0;
        lg[u][mi][1][r] = l1;
        // per-row tile-local max/sumexp (reduce over 16 m16 lanes)
        float mv = fmaxf(l0, l1);
        #pragma unroll
        for (int d = 1; d < 16; d <<= 1) mv = fmaxf(mv, __shfl_xor(mv, d));
        float se = __expf(l0 - mv) + __expf(l1 - mv);
        #pragma unroll
        for (int d = 1; d < 16; d <<= 1) se += __shfl_xor(se, d);
        if (m16 == 0){ mtile[t][row] = mv; stile[t][row] = se; }
      }
    }
  }
  __syncthreads();
  if (tid < 32){
    float gm = -1e30f;
    for (int t = 0; t < nt; ++t) gm = fmaxf(gm, mtile[t][tid]);
    float gs = 0.f;
    for (int t = 0; t < nt; ++t) gs += stile[t][tid]*__expf(mtile[t][tid] - gm);
    denl[tid] = gm + __logf(gs);
  }
  __syncthreads();
  #pragma unroll
  for (int u = 0; u < 2; ++u){
    int t = w + u*4;
    if (t >= nt) continue;
    #pragma unroll
    for (int ni = 0; ni < 2; ++ni){
      int j = t*32 + ni*16 + m16;
      if (j >= n) continue;
      float* outp = emit_col + (size_t)vj[u][ni]*32;
      #pragma unroll
      for (int mi = 0; mi < 2; ++mi)
        #pragma unroll
        for (int r = 0; r < 4; ++r){
          int row = mi*16 + q*4 + r;
          outp[row] = lg[u][mi][ni][r] - denl[row];
        }
    }
  }
}

// ---------------------------------------------------------------------------
// 32x32 product helpers (tree reduction)
__device__ inline void wave_norm_store(f32x4 acc[2][2], float* outp, int ostride,
                                       float sIn, float* sOut, int ln)
{
  int m16 = ln & 15, q = ln >> 4;
  float mx = 0.f;
  #pragma unroll
  for (int mi = 0; mi < 2; ++mi)
    #pragma unroll
    for (int ni = 0; ni < 2; ++ni)
      #pragma unroll
      for (int r = 0; r < 4; ++r) mx = fmaxf(mx, acc[mi][ni][r]);
  #pragma unroll
  for (int d = 1; d < 64; d <<= 1) mx = fmaxf(mx, __shfl_xor(mx, d));
  float inv = 1.0f/mx;
  #pragma unroll
  for (int mi = 0; mi < 2; ++mi)
    #pragma unroll
    for (int ni = 0; ni < 2; ++ni)
      #pragma unroll
      for (int r = 0; r < 4; ++r)
        outp[(mi*16 + q*4 + r)*ostride + ni*16 + m16] = acc[mi][ni][r]*inv;
  if (ln == 0) *sOut = sIn + __logf(mx);
}

__device__ inline void prod32(const float* L0, const float* L1, float* outp, int ostride,
                              float sIn, float* sOut, int ln)
{
  int m16 = ln & 15, q = ln >> 4;
  bf16x8 af[2], bfv[2];
  #pragma unroll
  for (int mi = 0; mi < 2; ++mi){
    const float* p = L0 + (mi*16 + m16)*MST + q*8;
    u16x8 u;
    #pragma unroll
    for (int jj = 0; jj < 8; ++jj) u[jj] = f2bf(p[jj]);
    af[mi] = __builtin_bit_cast(bf16x8, u);
  }
  #pragma unroll
  for (int ni = 0; ni < 2; ++ni){
    u16x8 u;
    #pragma unroll
    for (int jj = 0; jj < 8; ++jj) u[jj] = f2bf(L1[(q*8 + jj)*MST + ni*16 + m16]);
    bfv[ni] = __builtin_bit_cast(bf16x8, u);
  }
  f32x4 acc[2][2];
  #pragma unroll
  for (int mi = 0; mi < 2; ++mi)
    #pragma unroll
    for (int ni = 0; ni < 2; ++ni) acc[mi][ni] = (f32x4){0.f,0.f,0.f,0.f};
  #pragma unroll
  for (int mi = 0; mi < 2; ++mi)
    #pragma unroll
    for (int ni = 0; ni < 2; ++ni) acc[mi][ni] = mfma16(af[mi], bfv[ni], acc[mi][ni]);
  wave_norm_store(acc, outp, ostride, sIn, sOut, ln);
}

// ---------------------------------------------------------------------------
// k_chunk: one workgroup per (batch, chunk of 16 time-steps).
__global__ __launch_bounds__(512) void k_chunk(
  const unsigned short* __restrict__ Eap, const unsigned short* __restrict__ Ebp,
  const float* __restrict__ emit_col, const int* __restrict__ text,
  const int* __restrict__ w2s, float* __restrict__ Gm, float* __restrict__ Gs)
{
  __shared__ float bufL[16][32*MST];
  __shared__ float bufP[8][32*MST];
  __shared__ float sL[16], sA[8], sB[4], sC[2];
  int bc = blockIdx.x;
  int b = bc >> 4, ch = bc & 15;
  int w = threadIdx.x >> 6, ln = threadIdx.x & 63;
  int m16 = ln & 15, q = ln >> 4;
  for (int u = 0; u < 2; ++u){
    int l = 2*w + u;
    int s = ch*16 + l;
    float* outp = bufL[l];
    if (s >= 255){
      for (int i = ln; i < 32*32; i += 64){
        int r = i >> 5, c = i & 31;
        outp[r*MST + c] = (r == c) ? 1.f : 0.f;
      }
      if (ln == 0) sL[l] = 0.f;
    } else {
      int vp = text[b*256 + s], vc = text[b*256 + s + 1];
      int bp = w2s[vp*32], bq = w2s[vc*32];
      const unsigned short* a0 = Eap + (size_t)(bp + m16)*256 + q*8;
      const unsigned short* b0 = Ebp + (size_t)(bq + m16)*256 + q*8;
      f32x4 acc[2][2];
      #pragma unroll
      for (int mi = 0; mi < 2; ++mi)
        #pragma unroll
        for (int ni = 0; ni < 2; ++ni) acc[mi][ni] = (f32x4){0.f,0.f,0.f,0.f};
      #pragma unroll
      for (int kt = 0; kt < 8; ++kt){
        bf16x8 a_0 = *(const bf16x8*)(a0 + kt*32);
        bf16x8 a_1 = *(const bf16x8*)(a0 + 16*256 + kt*32);
        bf16x8 b_0 = *(const bf16x8*)(b0 + kt*32);
        bf16x8 b_1 = *(const bf16x8*)(b0 + 16*256 + kt*32);
        acc[0][0] = mfma16(a_0, b_0, acc[0][0]);
        acc[0][1] = mfma16(a_0, b_1, acc[0][1]);
        acc[1][0] = mfma16(a_1, b_0, acc[1][0]);
        acc[1][1] = mfma16(a_1, b_1, acc[1][1]);
      }
      float e0 = __expf(emit_col[(size_t)vc*32 + m16]);
      float e1 = __expf(emit_col[(size_t)vc*32 + 16 + m16]);
      #pragma unroll
      for (int mi = 0; mi < 2; ++mi)
        #pragma unroll
        for (int r = 0; r < 4; ++r){
          acc[mi][0][r] *= e0;
          acc[mi][1][r] *= e1;
        }
      wave_norm_store(acc, outp, MST, 0.f, &sL[l], ln);
    }
  }
  __syncthreads();
  prod32(bufL[2*w], bufL[2*w+1], bufP[w], MST, sL[2*w] + sL[2*w+1], &sA[w], ln);
  __syncthreads();
  if (w < 4) prod32(bufP[2*w], bufP[2*w+1], bufL[w], MST, sA[2*w] + sA[2*w+1], &sB[w], ln);
  __syncthreads();
  if (w < 2) prod32(bufL[2*w], bufL[2*w+1], bufP[w], MST, sB[2*w] + sB[2*w+1], &sC[w], ln);
  __syncthreads();
  if (w == 0) prod32(bufP[0], bufP[1], Gm + (size_t)bc*1024, 32, sC[0] + sC[1], Gs + bc, ln);
}

// ---------------------------------------------------------------------------
// k_root: per batch, reduce the 16 chunk matrices, then contract with alpha0.
__global__ __launch_bounds__(512) void k_root(
  const float* __restrict__ Gm, const float* __restrict__ Gs,
  const float* __restrict__ Eafx, const float* __restrict__ S,
  const unsigned short* __restrict__ Ebp, const float* __restrict__ emit_col,
  const int* __restrict__ text, const int* __restrict__ w2s, float* __restrict__ out)
{
  __shared__ float bufL[16][32*MST];
  __shared__ float bufP[8][32*MST];
  __shared__ float sL[16], sA[8], sB[4], sC[2], sD[1];
  int b = blockIdx.x;
  int w = threadIdx.x >> 6, ln = threadIdx.x & 63;
  for (int idx = threadIdx.x; idx < 16*1024; idx += 512){
    int i = idx >> 10, e = idx & 1023;
    bufL[i][(e >> 5)*MST + (e & 31)] = Gm[(size_t)(b*16 + i)*1024 + e];
  }
  if (threadIdx.x < 16) sL[threadIdx.x] = Gs[b*16 + threadIdx.x];
  __syncthreads();
  prod32(bufL[2*w], bufL[2*w+1], bufP[w], MST, sL[2*w] + sL[2*w+1], &sA[w], ln);
  __syncthreads();
  if (w < 4) prod32(bufP[2*w], bufP[2*w+1], bufL[w], MST, sA[2*w] + sA[2*w+1], &sB[w], ln);
  __syncthreads();
  if (w < 2) prod32(bufL[2*w], bufL[2*w+1], bufP[w], MST, sB[2*w] + sB[2*w+1], &sC[w], ln);
  __syncthreads();
  if (w == 0){
    prod32(bufP[0], bufP[1], bufL[0], MST, sC[0] + sC[1], &sD[0], ln);
    float part = 0.f;
    for (int d = ln; d < 256; d += 64) part = fmaf(Eafx[d], S[d], part);
    #pragma unroll
    for (int d2 = 1; d2 < 64; d2 <<= 1) part += __shfl_xor(part, d2);
    float dfx = part;
    int v0 = text[b*256];
    int k0 = w2s[v0*32];
    int j = ln & 31, h = ln >> 5;
    const unsigned short* er = Ebp + (size_t)(k0 + j)*256;
    float dot = 0.f;
    for (int d = h*128; d < h*128 + 128; ++d)
      dot = fmaf(Eafx[d], bf2f(er[d]), dot);
    dot += __shfl_xor(dot, 32);
    float z0 = __logf(dot) + emit_col[(size_t)v0*32 + j];
    float mz = z0;
    #pragma unroll
    for (int d2 = 1; d2 < 32; d2 <<= 1) mz = fmaxf(mz, __shfl_xor(mz, d2));
    float an = __expf(z0 - mz);
    float cs = 0.f;
    for (int i = h*16; i < h*16 + 16; ++i)
      cs = fmaf(__shfl(an, i), bufL[0][i*MST + j], cs);
    cs += __shfl_xor(cs, 32);
    float tot = cs;
    #pragma unroll
    for (int d2 = 1; d2 < 32; d2 <<= 1) tot += __shfl_xor(tot, d2);
    if (ln == 0) out[b] = __logf(tot) + mz + sD[0] - __logf(dfx);
  }
}

// ---------------------------------------------------------------------------
extern "C" void kernel_launch(void* const* d_in, const int* in_sizes, int n_in,
                              void* d_out, int out_size, void* d_ws, size_t ws_size,
                              hipStream_t stream)
{
  (void)in_sizes; (void)n_in; (void)out_size; (void)ws_size;
  const int*   text      = (const int*)  d_in[0];
  const float* start_emb = (const float*)d_in[1];
  const float* start_w   = (const float*)d_in[2];
  const float* start_b   = (const float*)d_in[3];
  const float* state_emb = (const float*)d_in[4];
  const float* next_emb  = (const float*)d_in[5];
  const float* pre_emb   = (const float*)d_in[6];
  const float* term_w    = (const float*)d_in[7];
  const float* term_b    = (const float*)d_in[8];
  const float* term_emb  = (const float*)d_in[9];
  const float* proj      = (const float*)d_in[10];
  const int*   w2s       = (const int*)  d_in[11];
  float* out = (float*)d_out;

  char* base = (char*)d_ws;
  size_t off = 0;
  auto alloc = [&](size_t bytes)->char*{
    char* p = base + off;
    off += (bytes + 255) & ~(size_t)255;
    return p;
  };
  unsigned short* projT = (unsigned short*)alloc((size_t)65536*2);
  unsigned short* WT    = (unsigned short*)alloc((size_t)4*65536*2);
  float* Eafx = (float*)alloc(256*4);
  float* H1   = (float*)alloc((size_t)C_*256*4);
  float* X2   = (float*)alloc((size_t)C_*256*4);
  float* FP   = (float*)alloc((size_t)C_*256*4);
  unsigned short* Epb = (unsigned short*)alloc((size_t)C_*256*2);
  float* mpp  = (float*)alloc((size_t)C_*4);
  unsigned short* Etb = (unsigned short*)alloc((size_t)V_*256*2);
  float* mt   = (float*)alloc((size_t)V_*4);
  float* S    = (float*)alloc(256*4);
  unsigned short* Eap = (unsigned short*)alloc((size_t)C_*256*2);
  unsigned short* Ebp = (unsigned short*)alloc((size_t)C_*256*2);
  int* cnt  = (int*)alloc(128*4);
  int* list = (int*)alloc((size_t)128*CAP_*4);
  float* emit_col = (float*)alloc((size_t)V_*32*4);
  float* Gm = (float*)alloc((size_t)256*1024*4);
  float* Gs = (float*)alloc((size_t)256*4);

  hipMemsetAsync(S, 0, 256*4, stream);
  hipMemsetAsync(cnt, 0, 128*4, stream);

  k_tpack<<<dim3(256,5), 256, 0, stream>>>(proj, term_w, projT, WT);
  k_lists<<<40, 256, 0, stream>>>(w2s, cnt, list);
  k_fx<<<1, 1024, 0, stream>>>(start_emb, start_w, start_b, proj, Eafx);

  // preterminal MLP (4 fused layers)
  k_mlp<<<128, 256, 0, stream>>>(pre_emb, WT + 0*65536, term_b + 0,   nullptr, H1);
  k_mlp<<<128, 256, 0, stream>>>(H1,      WT + 1*65536, term_b + 256, pre_emb, X2);
  k_mlp<<<128, 256, 0, stream>>>(X2,      WT + 2*65536, term_b + 512, nullptr, H1);
  k_mlp<<<128, 256, 0, stream>>>(H1,      WT + 3*65536, term_b + 768, X2,      FP);

  // phi kernels (fused pack+gemm+epilogue)
  k_phiB<<<128, 256, 0, stream>>>(next_emb, projT, Ebp, S);
  k_phiA<<<128, 256, 0, stream>>>(state_emb, projT, S, Eap);
  k_phiE<<<313, 256, 0, stream>>>(term_emb, projT, Etb, mt, V_);
  k_phiE<<<128, 256, 0, stream>>>(FP, projT, Epb, mpp, C_);

  k_emit<<<128, 256, 0, stream>>>(Epb, mpp, Etb, mt, cnt, list, emit_col);

  // tree reduction over transition-emission matrices
  k_chunk<<<256, 512, 0, stream>>>(Eap, Ebp, emit_col, text, w2s, Gm, Gs);
  k_root<<<16, 512, 0, stream>>>(Gm, Gs, Eafx, S, Ebp, emit_col, text, w2s, out);
}

// Round 5
// 251.636 us; speedup vs baseline: 2.1440x; 1.0846x over previous
//
#include <hip/hip_runtime.h>

#define B_   16
#define T_   256
#define V_   10000
#define C_   4096
#define H_   256
#define NC_  128
#define CAP_ 224
#define MST  33   // LDS matrix stride (32 + 1 pad), conflict-free transposed reads

typedef __bf16 bf16x8 __attribute__((ext_vector_type(8)));
typedef unsigned short u16x8 __attribute__((ext_vector_type(8)));
typedef float  f32x4  __attribute__((ext_vector_type(4)));

__device__ inline unsigned short f2bf(float f){
  unsigned int u = __float_as_uint(f);
  u += 0x7FFFu + ((u >> 16) & 1u);
  return (unsigned short)(u >> 16);
}
__device__ inline float bf2f(unsigned short u){
  return __uint_as_float(((unsigned int)u) << 16);
}
__device__ inline f32x4 mfma16(bf16x8 a, bf16x8 b, f32x4 c){
  return __builtin_amdgcn_mfma_f32_16x16x32_bf16(a, b, c, 0, 0, 0);
}
__device__ inline bf16x8 load_cvt8(const float* p){
  u16x8 u;
  #pragma unroll
  for (int i = 0; i < 8; ++i) u[i] = f2bf(p[i]);
  return __builtin_bit_cast(bf16x8, u);
}

// ===========================================================================
// MLP layer body: C[slab r0..r0+32) = res + relu(A @ Bt^T + bias)
__device__ inline void dev_mlp(const float* __restrict__ A,
    const unsigned short* __restrict__ Bt, const float* __restrict__ bias,
    const float* __restrict__ res, float* __restrict__ C, int r0)
{
  int tid = threadIdx.x;
  int w = tid >> 6, ln = tid & 63;
  int m16 = ln & 15, q = ln >> 4;
  int c0 = w*64;
  const float* a0 = A + (size_t)(r0 + m16)*256 + q*8;
  const float* a1 = a0 + 16*256;
  const unsigned short* bp0 = Bt + (size_t)(c0 + m16)*256 + q*8;
  f32x4 acc[2][4];
  #pragma unroll
  for (int i = 0; i < 2; ++i)
    #pragma unroll
    for (int jx = 0; jx < 4; ++jx) acc[i][jx] = (f32x4){0.f,0.f,0.f,0.f};
  #pragma unroll
  for (int kt = 0; kt < 8; ++kt){
    bf16x8 af0 = load_cvt8(a0 + kt*32);
    bf16x8 af1 = load_cvt8(a1 + kt*32);
    #pragma unroll
    for (int cj = 0; cj < 4; ++cj){
      bf16x8 bfj = *(const bf16x8*)(bp0 + (size_t)cj*16*256 + kt*32);
      acc[0][cj] = mfma16(af0, bfj, acc[0][cj]);
      acc[1][cj] = mfma16(af1, bfj, acc[1][cj]);
    }
  }
  #pragma unroll
  for (int ri = 0; ri < 2; ++ri){
    #pragma unroll
    for (int cj = 0; cj < 4; ++cj){
      #pragma unroll
      for (int r = 0; r < 4; ++r){
        int row = r0 + ri*16 + q*4 + r;
        int col = c0 + cj*16 + m16;
        float v = acc[ri][cj][r] + bias[col];
        v = fmaxf(v, 0.f);
        if (res) v += res[(size_t)row*256 + col];
        C[(size_t)row*256 + col] = v;
      }
    }
  }
}

// ===========================================================================
// phi GEMM core: 32-row slab x 256 cols, A fp32 cvt in-register; 0.5*||row||^2
__device__ inline void phi_core(const float* __restrict__ A,
    const unsigned short* __restrict__ Bt, int r0, int M, int w, int ln,
    f32x4 acc[2][4], float* lnrm)
{
  int m16 = ln & 15, q = ln >> 4;
  int c0 = w*64;
  int ra0 = r0 + m16;      if (ra0 > M-1) ra0 = M-1;
  int ra1 = r0 + 16 + m16; if (ra1 > M-1) ra1 = M-1;
  const float* a0 = A + (size_t)ra0*256 + q*8;
  const float* a1 = A + (size_t)ra1*256 + q*8;
  const unsigned short* bp0 = Bt + (size_t)(c0 + m16)*256 + q*8;
  float ss0 = 0.f, ss1 = 0.f;
  #pragma unroll
  for (int kt = 0; kt < 8; ++kt){
    float av0[8], av1[8];
    #pragma unroll
    for (int i2 = 0; i2 < 8; ++i2){ av0[i2] = a0[kt*32 + i2]; av1[i2] = a1[kt*32 + i2]; }
    u16x8 u0, u1;
    #pragma unroll
    for (int i2 = 0; i2 < 8; ++i2){
      u0[i2] = f2bf(av0[i2]); u1[i2] = f2bf(av1[i2]);
      ss0 = fmaf(av0[i2], av0[i2], ss0);
      ss1 = fmaf(av1[i2], av1[i2], ss1);
    }
    bf16x8 af0 = __builtin_bit_cast(bf16x8, u0);
    bf16x8 af1 = __builtin_bit_cast(bf16x8, u1);
    #pragma unroll
    for (int cj = 0; cj < 4; ++cj){
      bf16x8 bfj = *(const bf16x8*)(bp0 + (size_t)cj*16*256 + kt*32);
      acc[0][cj] = mfma16(af0, bfj, acc[0][cj]);
      acc[1][cj] = mfma16(af1, bfj, acc[1][cj]);
    }
  }
  ss0 += __shfl_xor(ss0, 16); ss0 += __shfl_xor(ss0, 32);
  ss1 += __shfl_xor(ss1, 16); ss1 += __shfl_xor(ss1, 32);
  if (w == 0 && q == 0){ lnrm[m16] = 0.5f*ss0; lnrm[16 + m16] = 0.5f*ss1; }
}

// ===========================================================================
// phiB epilogue: Ebp = bf16(exp(phi)), S += colsums (atomic)
__device__ inline void dev_phiB(const float* __restrict__ A,
    const unsigned short* __restrict__ projT, unsigned short* __restrict__ Ebp,
    float* __restrict__ S, int r0, float* lnrm)
{
  int tid = threadIdx.x;
  int w = tid >> 6, ln = tid & 63;
  int m16 = ln & 15, q = ln >> 4;
  f32x4 acc[2][4];
  #pragma unroll
  for (int i = 0; i < 2; ++i)
    #pragma unroll
    for (int jx = 0; jx < 4; ++jx) acc[i][jx] = (f32x4){0.f,0.f,0.f,0.f};
  phi_core(A, projT, r0, C_, w, ln, acc, lnrm);
  __syncthreads();
  int c0 = w*64;
  #pragma unroll
  for (int cj = 0; cj < 4; ++cj){
    int col = c0 + cj*16 + m16;
    float cs = 0.f;
    #pragma unroll
    for (int ri = 0; ri < 2; ++ri){
      #pragma unroll
      for (int r = 0; r < 4; ++r){
        int row = ri*16 + q*4 + r;
        float e = __expf(acc[ri][cj][r] - lnrm[row]);
        Ebp[(size_t)(r0 + row)*256 + col] = f2bf(e);
        cs += e;
      }
    }
    cs += __shfl_xor(cs, 16); cs += __shfl_xor(cs, 32);
    if (q == 0) atomicAdd(&S[col], cs);
  }
}

// ===========================================================================
// phiA epilogue: Eap = bf16( exp(phi - m) / sum_d exp(phi-m)*S[d] )
__device__ inline void dev_phiA(const float* __restrict__ A,
    const unsigned short* __restrict__ projT, const float* __restrict__ S,
    unsigned short* __restrict__ Eap, int r0,
    float* lnrm, float* sS, float (*wrow)[32], float (*wden)[32])
{
  int tid = threadIdx.x;
  int w = tid >> 6, ln = tid & 63;
  int m16 = ln & 15, q = ln >> 4;
  sS[tid] = S[tid];
  f32x4 acc[2][4];
  #pragma unroll
  for (int i = 0; i < 2; ++i)
    #pragma unroll
    for (int jx = 0; jx < 4; ++jx) acc[i][jx] = (f32x4){0.f,0.f,0.f,0.f};
  phi_core(A, projT, r0, C_, w, ln, acc, lnrm);
  __syncthreads();
  int c0 = w*64;
  #pragma unroll
  for (int ri = 0; ri < 2; ++ri){
    #pragma unroll
    for (int r = 0; r < 4; ++r){
      int row = ri*16 + q*4 + r;
      float mv = -1e30f;
      #pragma unroll
      for (int cj = 0; cj < 4; ++cj){
        acc[ri][cj][r] -= lnrm[row];
        mv = fmaxf(mv, acc[ri][cj][r]);
      }
      #pragma unroll
      for (int d = 1; d < 16; d <<= 1) mv = fmaxf(mv, __shfl_xor(mv, d));
      if (m16 == 0) wrow[w][row] = mv;
    }
  }
  __syncthreads();
  float ev[2][4][4];
  float dsum[2][4];
  #pragma unroll
  for (int ri = 0; ri < 2; ++ri){
    #pragma unroll
    for (int r = 0; r < 4; ++r){
      int row = ri*16 + q*4 + r;
      float m = fmaxf(fmaxf(wrow[0][row], wrow[1][row]), fmaxf(wrow[2][row], wrow[3][row]));
      dsum[ri][r] = 0.f;
      #pragma unroll
      for (int cj = 0; cj < 4; ++cj){
        float scol = sS[c0 + cj*16 + m16];
        float e = __expf(acc[ri][cj][r] - m);
        ev[ri][cj][r] = e;
        dsum[ri][r] = fmaf(e, scol, dsum[ri][r]);
      }
      #pragma unroll
      for (int d = 1; d < 16; d <<= 1) dsum[ri][r] += __shfl_xor(dsum[ri][r], d);
      if (m16 == 0) wden[w][row] = dsum[ri][r];
    }
  }
  __syncthreads();
  #pragma unroll
  for (int ri = 0; ri < 2; ++ri){
    #pragma unroll
    for (int r = 0; r < 4; ++r){
      int row = ri*16 + q*4 + r;
      float den = wden[0][row] + wden[1][row] + wden[2][row] + wden[3][row];
      float inv = 1.0f/den;
      #pragma unroll
      for (int cj = 0; cj < 4; ++cj){
        int col = c0 + cj*16 + m16;
        Eap[(size_t)(r0 + row)*256 + col] = f2bf(ev[ri][cj][r]*inv);
      }
    }
  }
}

// ===========================================================================
// phiE epilogue from acc: E = bf16(exp(phi - rowmax)), mr = rowmax
__device__ inline void phiE_epilogue(f32x4 acc[2][4], unsigned short* __restrict__ E,
    float* __restrict__ mr, int M, int r0, float* lnrm, float (*wrow)[32])
{
  int tid = threadIdx.x;
  int w = tid >> 6, ln = tid & 63;
  int m16 = ln & 15, q = ln >> 4;
  int c0 = w*64;
  #pragma unroll
  for (int ri = 0; ri < 2; ++ri){
    #pragma unroll
    for (int r = 0; r < 4; ++r){
      int row = ri*16 + q*4 + r;
      float mv = -1e30f;
      #pragma unroll
      for (int cj = 0; cj < 4; ++cj){
        acc[ri][cj][r] -= lnrm[row];
        mv = fmaxf(mv, acc[ri][cj][r]);
      }
      #pragma unroll
      for (int d = 1; d < 16; d <<= 1) mv = fmaxf(mv, __shfl_xor(mv, d));
      if (m16 == 0) wrow[w][row] = mv;
    }
  }
  __syncthreads();
  #pragma unroll
  for (int ri = 0; ri < 2; ++ri){
    #pragma unroll
    for (int r = 0; r < 4; ++r){
      int row = ri*16 + q*4 + r;
      int grow = r0 + row;
      float m = fmaxf(fmaxf(wrow[0][row], wrow[1][row]), fmaxf(wrow[2][row], wrow[3][row]));
      if (grow < M){
        #pragma unroll
        for (int cj = 0; cj < 4; ++cj){
          int col = c0 + cj*16 + m16;
          E[(size_t)grow*256 + col] = f2bf(__expf(acc[ri][cj][r] - m));
        }
        if (w == 0 && m16 == 0) mr[grow] = m;
      }
    }
  }
}

__device__ inline void dev_phiE(const float* __restrict__ A,
    const unsigned short* __restrict__ projT, unsigned short* __restrict__ E,
    float* __restrict__ mr, int M, int r0, float* lnrm, float (*wrow)[32])
{
  int tid = threadIdx.x;
  int w = tid >> 6, ln = tid & 63;
  f32x4 acc[2][4];
  #pragma unroll
  for (int i = 0; i < 2; ++i)
    #pragma unroll
    for (int jx = 0; jx < 4; ++jx) acc[i][jx] = (f32x4){0.f,0.f,0.f,0.f};
  phi_core(A, projT, r0, M, w, ln, acc, lnrm);
  __syncthreads();
  phiE_epilogue(acc, E, mr, M, r0, lnrm, wrow);
}

// ===========================================================================
// k_prep: fused tpack (blocks 0..1279) | lists (1280..1319) | fx (1320)
__global__ __launch_bounds__(256) void k_prep(
  const float* __restrict__ proj, const float* __restrict__ tw,
  unsigned short* __restrict__ projT, unsigned short* __restrict__ WT,
  const int* __restrict__ w2s, int* __restrict__ cnt, int* __restrict__ list,
  const float* __restrict__ se, const float* __restrict__ sw,
  const float* __restrict__ sb, float* __restrict__ Eafx)
{
  __shared__ float xv[256], hv[256], red[4];
  int bx = blockIdx.x, tid = threadIdx.x;
  if (bx < 1280){
    int z = bx >> 8, dcol = bx & 255;
    const float* src = (z == 0) ? proj : (tw + (size_t)(z-1)*65536);
    unsigned short* dst = (z == 0) ? projT : (WT + (size_t)(z-1)*65536);
    dst[dcol*256 + tid] = f2bf(src[tid*256 + dcol]);
    return;
  }
  if (bx < 1320){
    int v = (bx - 1280)*256 + tid;
    if (v < V_){
      int k = w2s[v*32] >> 5;
      int pos = atomicAdd(&cnt[k], 1);
      if (pos < CAP_) list[k*CAP_ + pos] = v;
    }
    return;
  }
  // fx arm
  int t = tid;
  hv[t] = se[t];
  __syncthreads();
  float acc = sb[t];
  for (int h = 0; h < 256; ++h) acc = fmaf(hv[h], sw[h*256 + t], acc);
  __syncthreads();
  xv[t] = acc;
  __syncthreads();
  acc = sb[256 + t];
  for (int h = 0; h < 256; ++h) acc = fmaf(xv[h], sw[65536 + h*256 + t], acc);
  hv[t] = fmaxf(acc, 0.f);
  __syncthreads();
  acc = sb[512 + t];
  for (int h = 0; h < 256; ++h) acc = fmaf(hv[h], sw[2*65536 + h*256 + t], acc);
  float xnew = xv[t] + fmaxf(acc, 0.f);
  __syncthreads();
  xv[t] = xnew;
  __syncthreads();
  acc = sb[768 + t];
  for (int h = 0; h < 256; ++h) acc = fmaf(xv[h], sw[3*65536 + h*256 + t], acc);
  hv[t] = fmaxf(acc, 0.f);
  __syncthreads();
  acc = sb[1024 + t];
  for (int h = 0; h < 256; ++h) acc = fmaf(hv[h], sw[4*65536 + h*256 + t], acc);
  xnew = xv[t] + fmaxf(acc, 0.f);
  __syncthreads();
  xv[t] = xnew;
  __syncthreads();
  float v2 = xv[t]*xv[t];
  #pragma unroll
  for (int m = 1; m < 64; m <<= 1) v2 += __shfl_xor(v2, m);
  if ((t & 63) == 0) red[t >> 6] = v2;
  __syncthreads();
  float nx = red[0]+red[1]+red[2]+red[3];
  float px = -0.5f*nx;
  for (int h = 0; h < 256; ++h) px = fmaf(xv[h], proj[h*256 + t], px);
  __syncthreads();
  float m2 = px;
  #pragma unroll
  for (int m = 1; m < 64; m <<= 1) m2 = fmaxf(m2, __shfl_xor(m2, m));
  if ((t & 63) == 0) red[t >> 6] = m2;
  __syncthreads();
  m2 = fmaxf(fmaxf(red[0], red[1]), fmaxf(red[2], red[3]));
  Eafx[t] = __expf(px - m2);
}

// ===========================================================================
// k_big1: mlp L0 (0..127) | phiB (128..255) | phiE(term_emb) (256..568)
__global__ __launch_bounds__(256) void k_big1(
  const float* __restrict__ pre_emb, const unsigned short* __restrict__ WT,
  const float* __restrict__ term_b, float* __restrict__ H1,
  const float* __restrict__ next_emb, const unsigned short* __restrict__ projT,
  unsigned short* __restrict__ Ebp, float* __restrict__ S,
  const float* __restrict__ term_emb, unsigned short* __restrict__ Etb,
  float* __restrict__ mt)
{
  __shared__ float lnrm[32];
  __shared__ float wrow[4][32];
  int bx = blockIdx.x;
  if (bx < 128){
    dev_mlp(pre_emb, WT, term_b, nullptr, H1, bx*32);
  } else if (bx < 256){
    dev_phiB(next_emb, projT, Ebp, S, (bx - 128)*32, lnrm);
  } else {
    dev_phiE(term_emb, projT, Etb, mt, V_, (bx - 256)*32, lnrm, wrow);
  }
}

// ===========================================================================
// k_big2: mlp L1 (0..127) | phiA (128..255)
__global__ __launch_bounds__(256) void k_big2(
  const float* __restrict__ H1, const unsigned short* __restrict__ WT,
  const float* __restrict__ term_b, const float* __restrict__ pre_emb,
  float* __restrict__ X2,
  const float* __restrict__ state_emb, const unsigned short* __restrict__ projT,
  const float* __restrict__ S, unsigned short* __restrict__ Eap)
{
  __shared__ float lnrm[32];
  __shared__ float sS[256];
  __shared__ float wrow[4][32];
  __shared__ float wden[4][32];
  int bx = blockIdx.x;
  if (bx < 128){
    dev_mlp(H1, WT + 1*65536, term_b + 256, pre_emb, X2, bx*32);
  } else {
    dev_phiA(state_emb, projT, S, Eap, (bx - 128)*32, lnrm, sS, wrow, wden);
  }
}

// ===========================================================================
// k_mlpL2: H1 = relu(X2 @ W2 + b2)
__global__ __launch_bounds__(256) void k_mlpL2(
  const float* __restrict__ X2, const unsigned short* __restrict__ WT2,
  const float* __restrict__ bias, float* __restrict__ H1)
{
  dev_mlp(X2, WT2, bias, nullptr, H1, blockIdx.x*32);
}

// ===========================================================================
// k_mlp3phi: FP-slab = X2 + relu(H1 @ W3 + b3) in LDS, then phi -> Epb, mpp
__global__ __launch_bounds__(256) void k_mlp3phi(
  const float* __restrict__ H1, const unsigned short* __restrict__ WT3,
  const float* __restrict__ bias, const float* __restrict__ X2,
  const unsigned short* __restrict__ projT, unsigned short* __restrict__ Epb,
  float* __restrict__ mpp)
{
  __shared__ float sFP[32*257];
  __shared__ float lnrm[32];
  __shared__ float wrow[4][32];
  int r0 = blockIdx.x*32;
  int tid = threadIdx.x;
  int w = tid >> 6, ln = tid & 63;
  int m16 = ln & 15, q = ln >> 4;
  int c0 = w*64;
  // stage 1: mlp L3 into sFP
  {
    const float* a0 = H1 + (size_t)(r0 + m16)*256 + q*8;
    const float* a1 = a0 + 16*256;
    const unsigned short* bp0 = WT3 + (size_t)(c0 + m16)*256 + q*8;
    f32x4 acc[2][4];
    #pragma unroll
    for (int i = 0; i < 2; ++i)
      #pragma unroll
      for (int jx = 0; jx < 4; ++jx) acc[i][jx] = (f32x4){0.f,0.f,0.f,0.f};
    #pragma unroll
    for (int kt = 0; kt < 8; ++kt){
      bf16x8 af0 = load_cvt8(a0 + kt*32);
      bf16x8 af1 = load_cvt8(a1 + kt*32);
      #pragma unroll
      for (int cj = 0; cj < 4; ++cj){
        bf16x8 bfj = *(const bf16x8*)(bp0 + (size_t)cj*16*256 + kt*32);
        acc[0][cj] = mfma16(af0, bfj, acc[0][cj]);
        acc[1][cj] = mfma16(af1, bfj, acc[1][cj]);
      }
    }
    #pragma unroll
    for (int ri = 0; ri < 2; ++ri){
      #pragma unroll
      for (int cj = 0; cj < 4; ++cj){
        #pragma unroll
        for (int r = 0; r < 4; ++r){
          int row = ri*16 + q*4 + r;
          int col = c0 + cj*16 + m16;
          float v = acc[ri][cj][r] + bias[col];
          v = fmaxf(v, 0.f);
          v += X2[(size_t)(r0 + row)*256 + col];
          sFP[row*257 + col] = v;
        }
      }
    }
  }
  __syncthreads();
  // stage 2: phi from LDS slab
  f32x4 acc[2][4];
  #pragma unroll
  for (int i = 0; i < 2; ++i)
    #pragma unroll
    for (int jx = 0; jx < 4; ++jx) acc[i][jx] = (f32x4){0.f,0.f,0.f,0.f};
  {
    const float* a0 = sFP + m16*257 + q*8;
    const float* a1 = sFP + (16 + m16)*257 + q*8;
    const unsigned short* bp0 = projT + (size_t)(c0 + m16)*256 + q*8;
    float ss0 = 0.f, ss1 = 0.f;
    #pragma unroll
    for (int kt = 0; kt < 8; ++kt){
      float av0[8], av1[8];
      #pragma unroll
      for (int i2 = 0; i2 < 8; ++i2){ av0[i2] = a0[kt*32 + i2]; av1[i2] = a1[kt*32 + i2]; }
      u16x8 u0, u1;
      #pragma unroll
      for (int i2 = 0; i2 < 8; ++i2){
        u0[i2] = f2bf(av0[i2]); u1[i2] = f2bf(av1[i2]);
        ss0 = fmaf(av0[i2], av0[i2], ss0);
        ss1 = fmaf(av1[i2], av1[i2], ss1);
      }
      bf16x8 af0 = __builtin_bit_cast(bf16x8, u0);
      bf16x8 af1 = __builtin_bit_cast(bf16x8, u1);
      #pragma unroll
      for (int cj = 0; cj < 4; ++cj){
        bf16x8 bfj = *(const bf16x8*)(bp0 + (size_t)cj*16*256 + kt*32);
        acc[0][cj] = mfma16(af0, bfj, acc[0][cj]);
        acc[1][cj] = mfma16(af1, bfj, acc[1][cj]);
      }
    }
    ss0 += __shfl_xor(ss0, 16); ss0 += __shfl_xor(ss0, 32);
    ss1 += __shfl_xor(ss1, 16); ss1 += __shfl_xor(ss1, 32);
    if (w == 0 && q == 0){ lnrm[m16] = 0.5f*ss0; lnrm[16 + m16] = 0.5f*ss1; }
  }
  __syncthreads();
  phiE_epilogue(acc, Epb, mpp, C_, r0, lnrm, wrow);
}

// ===========================================================================
// k_emit: per-cluster emit log-softmax via MFMA
__global__ __launch_bounds__(256) void k_emit(
    const unsigned short* __restrict__ Epb, const float* __restrict__ mp,
    const unsigned short* __restrict__ Etb, const float* __restrict__ mt,
    const int* __restrict__ cnt, const int* __restrict__ list,
    float* __restrict__ emit_col)
{
  __shared__ float mtile[8][32];
  __shared__ float stile[8][32];
  __shared__ float mpl[32];
  __shared__ float denl[32];
  int k = blockIdx.x, tid = threadIdx.x;
  int w = tid >> 6, ln = tid & 63;
  int m16 = ln & 15, q = ln >> 4;
  if (tid < 32) mpl[tid] = mp[k*32 + tid];
  int n = cnt[k]; if (n > CAP_) n = CAP_;
  int nt = (n + 31) >> 5;
  const int* lp = list + k*CAP_;
  bf16x8 af0[8], af1[8];
  {
    const unsigned short* ap0 = Epb + (size_t)(k*32 + m16)*256 + q*8;
    const unsigned short* ap1 = ap0 + 16*256;
    #pragma unroll
    for (int kt = 0; kt < 8; ++kt){
      af0[kt] = *(const bf16x8*)(ap0 + kt*32);
      af1[kt] = *(const bf16x8*)(ap1 + kt*32);
    }
  }
  float lg[2][2][2][4];
  int   vj[2][2];
  #pragma unroll
  for (int u = 0; u < 2; ++u){
    int t = w + u*4;
    if (t >= nt) continue;
    int j0 = t*32 + m16, j1 = j0 + 16;
    int v0 = lp[(j0 < n) ? j0 : 0];
    int v1 = lp[(j1 < n) ? j1 : 0];
    vj[u][0] = v0; vj[u][1] = v1;
    float mt0 = (j0 < n) ? mt[v0] : 0.f;
    float mt1 = (j1 < n) ? mt[v1] : 0.f;
    const unsigned short* bp0 = Etb + (size_t)v0*256 + q*8;
    const unsigned short* bp1 = Etb + (size_t)v1*256 + q*8;
    f32x4 acc[2][2];
    #pragma unroll
    for (int mi = 0; mi < 2; ++mi)
      #pragma unroll
      for (int ni = 0; ni < 2; ++ni) acc[mi][ni] = (f32x4){0.f,0.f,0.f,0.f};
    #pragma unroll
    for (int kt = 0; kt < 8; ++kt){
      bf16x8 b0 = *(const bf16x8*)(bp0 + kt*32);
      bf16x8 b1 = *(const bf16x8*)(bp1 + kt*32);
      acc[0][0] = mfma16(af0[kt], b0, acc[0][0]);
      acc[0][1] = mfma16(af0[kt], b1, acc[0][1]);
      acc[1][0] = mfma16(af1[kt], b0, acc[1][0]);
      acc[1][1] = mfma16(af1[kt], b1, acc[1][1]);
    }
    #pragma unroll
    for (int mi = 0; mi < 2; ++mi){
      #pragma unroll
      for (int r = 0; r < 4; ++r){
        int row = mi*16 + q*4 + r;
        float l0 = (j0 < n) ? (__logf(acc[mi][0][r]) + mpl[row] + mt0) : -1e30f;
        float l1 = (j1 < n) ? (__logf(acc[mi][1][r]) + mpl[row] + mt1) : -1e30f;
        lg[u][mi][0][r] = l0;
        lg[u][mi][1][r] = l1;
        float mv = fmaxf(l0, l1);
        #pragma unroll
        for (int d = 1; d < 16; d <<= 1) mv = fmaxf(mv, __shfl_xor(mv, d));
        float se = __expf(l0 - mv) + __expf(l1 - mv);
        #pragma unroll
        for (int d = 1; d < 16; d <<= 1) se += __shfl_xor(se, d);
        if (m16 == 0){ mtile[t][row] = mv; stile[t][row] = se; }
      }
    }
  }
  __syncthreads();
  if (tid < 32){
    float gm = -1e30f;
    for (int t = 0; t < nt; ++t) gm = fmaxf(gm, mtile[t][tid]);
    float gs = 0.f;
    for (int t = 0; t < nt; ++t) gs += stile[t][tid]*__expf(mtile[t][tid] - gm);
    denl[tid] = gm + __logf(gs);
  }
  __syncthreads();
  #pragma unroll
  for (int u = 0; u < 2; ++u){
    int t = w + u*4;
    if (t >= nt) continue;
    #pragma unroll
    for (int ni = 0; ni < 2; ++ni){
      int j = t*32 + ni*16 + m16;
      if (j >= n) continue;
      float* outp = emit_col + (size_t)vj[u][ni]*32;
      #pragma unroll
      for (int mi = 0; mi < 2; ++mi)
        #pragma unroll
        for (int r = 0; r < 4; ++r){
          int row = mi*16 + q*4 + r;
          outp[row] = lg[u][mi][ni][r] - denl[row];
        }
    }
  }
}

// ===========================================================================
// 32x32 product helpers
__device__ inline void prod_acc(const float* __restrict__ L0, const float* __restrict__ L1,
                                f32x4 acc[2][2], int ln)
{
  int m16 = ln & 15, q = ln >> 4;
  bf16x8 af[2], bfv[2];
  #pragma unroll
  for (int mi = 0; mi < 2; ++mi){
    const float* p = L0 + (mi*16 + m16)*MST + q*8;
    u16x8 u;
    #pragma unroll
    for (int jj = 0; jj < 8; ++jj) u[jj] = f2bf(p[jj]);
    af[mi] = __builtin_bit_cast(bf16x8, u);
  }
  #pragma unroll
  for (int ni = 0; ni < 2; ++ni){
    u16x8 u;
    #pragma unroll
    for (int jj = 0; jj < 8; ++jj) u[jj] = f2bf(L1[(q*8 + jj)*MST + ni*16 + m16]);
    bfv[ni] = __builtin_bit_cast(bf16x8, u);
  }
  #pragma unroll
  for (int mi = 0; mi < 2; ++mi)
    #pragma unroll
    for (int ni = 0; ni < 2; ++ni) acc[mi][ni] = mfma16(af[mi], bfv[ni], acc[mi][ni]);
}

__device__ inline void wave_norm_store(f32x4 acc[2][2], float* outp,
                                       float sIn, float* sOut, int ln)
{
  int m16 = ln & 15, q = ln >> 4;
  float mx = 0.f;
  #pragma unroll
  for (int mi = 0; mi < 2; ++mi)
    #pragma unroll
    for (int ni = 0; ni < 2; ++ni)
      #pragma unroll
      for (int r = 0; r < 4; ++r) mx = fmaxf(mx, acc[mi][ni][r]);
  #pragma unroll
  for (int d = 1; d < 64; d <<= 1) mx = fmaxf(mx, __shfl_xor(mx, d));
  float inv = 1.0f/mx;
  #pragma unroll
  for (int mi = 0; mi < 2; ++mi)
    #pragma unroll
    for (int ni = 0; ni < 2; ++ni)
      #pragma unroll
      for (int r = 0; r < 4; ++r)
        outp[(mi*16 + q*4 + r)*MST + ni*16 + m16] = acc[mi][ni][r]*inv;
  if (ln == 0) *sOut = sIn + __logf(mx);
}

__device__ inline void norm_store_g16(f32x4 acc[2][2], unsigned short* outp,
                                      float sIn, float* sOutG, int ln)
{
  int m16 = ln & 15, q = ln >> 4;
  float mx = 0.f;
  #pragma unroll
  for (int mi = 0; mi < 2; ++mi)
    #pragma unroll
    for (int ni = 0; ni < 2; ++ni)
      #pragma unroll
      for (int r = 0; r < 4; ++r) mx = fmaxf(mx, acc[mi][ni][r]);
  #pragma unroll
  for (int d = 1; d < 64; d <<= 1) mx = fmaxf(mx, __shfl_xor(mx, d));
  float inv = 1.0f/mx;
  #pragma unroll
  for (int mi = 0; mi < 2; ++mi)
    #pragma unroll
    for (int ni = 0; ni < 2; ++ni)
      #pragma unroll
      for (int r = 0; r < 4; ++r)
        outp[(mi*16 + q*4 + r)*32 + ni*16 + m16] = f2bf(acc[mi][ni][r]*inv);
  if (ln == 0) *sOutG = sIn + __logf(mx);
}

__device__ inline void prod32(const float* L0, const float* L1, float* outp,
                              float sIn, float* sOut, int ln)
{
  f32x4 acc[2][2];
  #pragma unroll
  for (int mi = 0; mi < 2; ++mi)
    #pragma unroll
    for (int ni = 0; ni < 2; ++ni) acc[mi][ni] = (f32x4){0.f,0.f,0.f,0.f};
  prod_acc(L0, L1, acc, ln);
  wave_norm_store(acc, outp, sIn, sOut, ln);
}

// ===========================================================================
// k_chunk: one WG per (batch, chunk of 8 leaves). 4 waves, barrier-light.
__global__ __launch_bounds__(256) void k_chunk(
  const unsigned short* __restrict__ Eap, const unsigned short* __restrict__ Ebp,
  const float* __restrict__ emit_col, const int* __restrict__ text,
  const int* __restrict__ w2s, unsigned short* __restrict__ Gm, float* __restrict__ Gs)
{
  __shared__ float bufL[8][32*MST];
  __shared__ float bufN[4][32*MST];
  __shared__ float sL[8], sN[4], sT[2];
  int bc = blockIdx.x;              // 0..511
  int b = bc >> 5, ch = bc & 31;
  int tid = threadIdx.x;
  int w = tid >> 6, ln = tid & 63;
  int m16 = ln & 15, q = ln >> 4;
  #pragma unroll
  for (int u = 0; u < 2; ++u){
    int l = 2*w + u;
    int s = ch*8 + l;               // transition step t = s+1
    float* outp = bufL[l];
    if (s >= 255){
      for (int i = ln; i < 32*32; i += 64){
        int r = i >> 5, c = i & 31;
        outp[r*MST + c] = (r == c) ? 1.f : 0.f;
      }
      if (ln == 0) sL[l] = 0.f;
    } else {
      int vp = text[b*256 + s], vc = text[b*256 + s + 1];
      int bp = w2s[vp*32], bq = w2s[vc*32];
      const unsigned short* a0 = Eap + (size_t)(bp + m16)*256 + q*8;
      const unsigned short* b0 = Ebp + (size_t)(bq + m16)*256 + q*8;
      f32x4 acc[2][2];
      #pragma unroll
      for (int mi = 0; mi < 2; ++mi)
        #pragma unroll
        for (int ni = 0; ni < 2; ++ni) acc[mi][ni] = (f32x4){0.f,0.f,0.f,0.f};
      #pragma unroll
      for (int kt = 0; kt < 8; ++kt){
        bf16x8 a_0 = *(const bf16x8*)(a0 + kt*32);
        bf16x8 a_1 = *(const bf16x8*)(a0 + 16*256 + kt*32);
        bf16x8 b_0 = *(const bf16x8*)(b0 + kt*32);
        bf16x8 b_1 = *(const bf16x8*)(b0 + 16*256 + kt*32);
        acc[0][0] = mfma16(a_0, b_0, acc[0][0]);
        acc[0][1] = mfma16(a_0, b_1, acc[0][1]);
        acc[1][0] = mfma16(a_1, b_0, acc[1][0]);
        acc[1][1] = mfma16(a_1, b_1, acc[1][1]);
      }
      float e0 = __expf(emit_col[(size_t)vc*32 + m16]);
      float e1 = __expf(emit_col[(size_t)vc*32 + 16 + m16]);
      #pragma unroll
      for (int mi = 0; mi < 2; ++mi)
        #pragma unroll
        for (int r = 0; r < 4; ++r){
          acc[mi][0][r] *= e0;
          acc[mi][1][r] *= e1;
        }
      wave_norm_store(acc, outp, 0.f, &sL[l], ln);
    }
  }
  // pair product, wave-private (no barrier)
  prod32(bufL[2*w], bufL[2*w+1], bufN[w], sL[2*w] + sL[2*w+1], &sN[w], ln);
  __syncthreads();
  if (w == 0){
    prod32(bufN[0], bufN[1], bufL[0], sN[0] + sN[1], &sT[0], ln);
    prod32(bufL[0], bufN[2], bufL[1], sT[0] + sN[2], &sT[1], ln);
    f32x4 acc[2][2];
    #pragma unroll
    for (int mi = 0; mi < 2; ++mi)
      #pragma unroll
      for (int ni = 0; ni < 2; ++ni) acc[mi][ni] = (f32x4){0.f,0.f,0.f,0.f};
    prod_acc(bufL[1], bufN[3], acc, ln);
    norm_store_g16(acc, Gm + (size_t)bc*1024, sT[1] + sN[3], Gs + bc, ln);
  }
}

// ===========================================================================
__device__ inline void load_mat16(const unsigned short* __restrict__ g,
                                  float* __restrict__ d, int ln){
  #pragma unroll
  for (int p = 0; p < 16; ++p){
    int idx = p*64 + ln;
    int r = idx >> 5, c = idx & 31;
    d[r*MST + c] = bf2f(g[idx]);
  }
}

// k_root: per batch, 8 waves each serially reduce 4 chunk matrices, then
// wave 0 combines 8 nodes and contracts with analytic alpha0.
__global__ __launch_bounds__(512) void k_root(
  const unsigned short* __restrict__ Gm, const float* __restrict__ Gs,
  const float* __restrict__ Eafx, const float* __restrict__ S,
  const unsigned short* __restrict__ Ebp, const float* __restrict__ emit_col,
  const int* __restrict__ text, const int* __restrict__ w2s, float* __restrict__ out)
{
  __shared__ float W[8][3][32*MST];
  __shared__ float sW[8], sT[1];
  int b = blockIdx.x;
  int tid = threadIdx.x;
  int w = tid >> 6, ln = tid & 63;
  const unsigned short* G = Gm + ((size_t)(b*32 + w*4))*1024;
  const float* gs = Gs + b*32 + w*4;
  load_mat16(G,        W[w][0], ln);
  load_mat16(G + 1024, W[w][1], ln);
  prod32(W[w][0], W[w][1], W[w][2], gs[0] + gs[1], &sW[w], ln);
  load_mat16(G + 2048, W[w][0], ln);
  prod32(W[w][2], W[w][0], W[w][1], sW[w] + gs[2], &sW[w], ln);
  load_mat16(G + 3072, W[w][0], ln);
  prod32(W[w][1], W[w][0], W[w][2], sW[w] + gs[3], &sW[w], ln);
  __syncthreads();
  if (w == 0){
    float sAcc = sW[0];
    const float* cur = W[0][2];
    int dsel = 0;
    for (int j = 1; j < 8; ++j){
      float* dst = dsel ? W[0][1] : W[0][0];
      prod32(cur, W[j][2], dst, sAcc + sW[j], &sT[0], ln);
      sAcc = sT[0];
      cur = dst;
      dsel ^= 1;
    }
    // alpha0 analytic: start_lp[c] = log(Eafx.Ebp[c]) - log(Eafx.S)
    float part = 0.f;
    for (int d = ln; d < 256; d += 64) part = fmaf(Eafx[d], S[d], part);
    #pragma unroll
    for (int d2 = 1; d2 < 64; d2 <<= 1) part += __shfl_xor(part, d2);
    float dfx = part;
    int v0 = text[b*256];
    int k0 = w2s[v0*32];
    int j = ln & 31, h = ln >> 5;
    const unsigned short* er = Ebp + (size_t)(k0 + j)*256;
    float dot = 0.f;
    for (int d = h*128; d < h*128 + 128; ++d)
      dot = fmaf(Eafx[d], bf2f(er[d]), dot);
    dot += __shfl_xor(dot, 32);
    float z0 = __logf(dot) + emit_col[(size_t)v0*32 + j];
    float mz = z0;
    #pragma unroll
    for (int d2 = 1; d2 < 32; d2 <<= 1) mz = fmaxf(mz, __shfl_xor(mz, d2));
    float an = __expf(z0 - mz);
    float cs = 0.f;
    for (int i = h*16; i < h*16 + 16; ++i)
      cs = fmaf(__shfl(an, i), cur[i*MST + j], cs);
    cs += __shfl_xor(cs, 32);
    float tot = cs;
    #pragma unroll
    for (int d2 = 1; d2 < 32; d2 <<= 1) tot += __shfl_xor(tot, d2);
    if (ln == 0) out[b] = __logf(tot) + mz + sAcc - __logf(dfx);
  }
}

// ===========================================================================
extern "C" void kernel_launch(void* const* d_in, const int* in_sizes, int n_in,
                              void* d_out, int out_size, void* d_ws, size_t ws_size,
                              hipStream_t stream)
{
  (void)in_sizes; (void)n_in; (void)out_size; (void)ws_size;
  const int*   text      = (const int*)  d_in[0];
  const float* start_emb = (const float*)d_in[1];
  const float* start_w   = (const float*)d_in[2];
  const float* start_b   = (const float*)d_in[3];
  const float* state_emb = (const float*)d_in[4];
  const float* next_emb  = (const float*)d_in[5];
  const float* pre_emb   = (const float*)d_in[6];
  const float* term_w    = (const float*)d_in[7];
  const float* term_b    = (const float*)d_in[8];
  const float* term_emb  = (const float*)d_in[9];
  const float* proj      = (const float*)d_in[10];
  const int*   w2s       = (const int*)  d_in[11];
  float* out = (float*)d_out;

  char* base = (char*)d_ws;
  size_t off = 0;
  auto alloc = [&](size_t bytes)->char*{
    char* p = base + off;
    off += (bytes + 255) & ~(size_t)255;
    return p;
  };
  unsigned short* projT = (unsigned short*)alloc((size_t)65536*2);
  unsigned short* WT    = (unsigned short*)alloc((size_t)4*65536*2);
  float* Eafx = (float*)alloc(256*4);
  float* H1   = (float*)alloc((size_t)C_*256*4);
  float* X2   = (float*)alloc((size_t)C_*256*4);
  unsigned short* Epb = (unsigned short*)alloc((size_t)C_*256*2);
  float* mpp  = (float*)alloc((size_t)C_*4);
  unsigned short* Etb = (unsigned short*)alloc((size_t)V_*256*2);
  float* mt   = (float*)alloc((size_t)V_*4);
  float* S    = (float*)alloc(256*4);
  unsigned short* Eap = (unsigned short*)alloc((size_t)C_*256*2);
  unsigned short* Ebp = (unsigned short*)alloc((size_t)C_*256*2);
  int* cnt  = (int*)alloc(128*4);
  int* list = (int*)alloc((size_t)128*CAP_*4);
  float* emit_col = (float*)alloc((size_t)V_*32*4);
  unsigned short* Gm = (unsigned short*)alloc((size_t)512*1024*2);
  float* Gs = (float*)alloc((size_t)512*4);

  (void)hipMemsetAsync(S, 0, 256*4, stream);
  (void)hipMemsetAsync(cnt, 0, 128*4, stream);

  k_prep<<<1321, 256, 0, stream>>>(proj, term_w, projT, WT, w2s, cnt, list,
                                   start_emb, start_w, start_b, Eafx);
  k_big1<<<569, 256, 0, stream>>>(pre_emb, WT, term_b, H1,
                                  next_emb, projT, Ebp, S,
                                  term_emb, Etb, mt);
  k_big2<<<256, 256, 0, stream>>>(H1, WT, term_b, pre_emb, X2,
                                  state_emb, projT, S, Eap);
  k_mlpL2<<<128, 256, 0, stream>>>(X2, WT + 2*65536, term_b + 512, H1);
  k_mlp3phi<<<128, 256, 0, stream>>>(H1, WT + 3*65536, term_b + 768, X2,
                                     projT, Epb, mpp);
  k_emit<<<128, 256, 0, stream>>>(Epb, mpp, Etb, mt, cnt, list, emit_col);
  k_chunk<<<512, 256, 0, stream>>>(Eap, Ebp, emit_col, text, w2s, Gm, Gs);
  k_root<<<16, 512, 0, stream>>>(Gm, Gs, Eafx, S, Ebp, emit_col, text, w2s, out);
}